// Round 1
// baseline (614.264 us; speedup 1.0000x reference)
//
#include <hip/hip_runtime.h>
#include <hip/hip_bf16.h>
#include <math.h>

#define NN 65536
#define NE 1048576
#define D 128
#define DP 129
#define EPSF 1e-6f

__global__ void k_zero(int* p, int n) {
    int i = blockIdx.x * blockDim.x + threadIdx.x;
    if (i < n) p[i] = 0;
}

__global__ void k_hist(const int* __restrict__ dst, int E, int* __restrict__ deg) {
    int i = blockIdx.x * blockDim.x + threadIdx.x;
    if (i < E) atomicAdd(&deg[dst[i]], 1);
}

__global__ __launch_bounds__(1024) void k_scan(const int* __restrict__ deg,
                                               int* __restrict__ off,
                                               int* __restrict__ cursor, int n) {
    __shared__ int sh[1024];
    int t = threadIdx.x;
    int per = n / 1024;  // 64
    int base = t * per;
    int sum = 0;
    for (int j = 0; j < per; ++j) sum += deg[base + j];
    sh[t] = sum;
    __syncthreads();
    // Hillis-Steele inclusive scan (read-all, barrier, write-all)
    for (int ofs = 1; ofs < 1024; ofs <<= 1) {
        int v = (t >= ofs) ? sh[t - ofs] : 0;
        __syncthreads();
        sh[t] += v;
        __syncthreads();
    }
    int run = sh[t] - sum;  // exclusive prefix
    for (int j = 0; j < per; ++j) {
        off[base + j] = run;
        cursor[base + j] = run;
        run += deg[base + j];
    }
}

__global__ void k_scatter(const int* __restrict__ src, const int* __restrict__ dst,
                          int E, int* __restrict__ cursor, int* __restrict__ ssrc) {
    int i = blockIdx.x * blockDim.x + threadIdx.x;
    if (i < E) {
        int d = dst[i];
        int p = atomicAdd(&cursor[d], 1);
        ssrc[p] = src[i];
    }
}

__global__ void k_transpose(const float* __restrict__ W, float* __restrict__ WT) {
    int i = blockIdx.x * blockDim.x + threadIdx.x;  // 16384
    if (i < D * D) {
        int k = i >> 7, j = i & 127;
        WT[i] = W[j * D + k];  // WT[k][j] = W[j][k]
    }
}

// z[r][j] = sum_k log0(x[r])[k] * W[j][k] + b[j]
// log0(x)[k] = arccosh(max(x0,1+eps)) / max(||xs||,eps) * xs[k]
__global__ __launch_bounds__(256) void k_gemm(const float* __restrict__ x,
                                              const float* __restrict__ WT,
                                              const float* __restrict__ b,
                                              float* __restrict__ z) {
    __shared__ float A[64][132];  // pitch 132 to kill bank conflicts
    int t = threadIdx.x;
    int wave = t >> 6, lane = t & 63;
    int r0 = blockIdx.x * 64;

    // phase 1: compute log0 rows into LDS
    for (int rl = wave; rl < 64; rl += 4) {
        const float* xr = x + (size_t)(r0 + rl) * DP;
        float x0 = xr[0];
        float a0 = xr[1 + lane];
        float a1 = xr[1 + 64 + lane];
        float ss = a0 * a0 + a1 * a1;
        #pragma unroll
        for (int o = 1; o < 64; o <<= 1) ss += __shfl_xor(ss, o);
        float xn = sqrtf(fmaxf(ss, EPSF * EPSF));
        float theta = acoshf(fmaxf(x0, 1.0f + EPSF));
        float f = theta / xn;
        A[rl][lane] = f * a0;
        A[rl][64 + lane] = f * a1;
    }
    __syncthreads();

    // phase 2: 256 threads; thread = (ty,tx): rows ty*8..+7, cols tx*4..+3
    int tx = t & 31, ty = t >> 5;
    float acc[8][4];
    float4 bb = *(const float4*)&b[tx * 4];
    #pragma unroll
    for (int i = 0; i < 8; ++i) {
        acc[i][0] = bb.x; acc[i][1] = bb.y; acc[i][2] = bb.z; acc[i][3] = bb.w;
    }
    #pragma unroll 4
    for (int k = 0; k < D; k += 4) {
        float4 w0 = *(const float4*)&WT[(k + 0) * D + tx * 4];
        float4 w1 = *(const float4*)&WT[(k + 1) * D + tx * 4];
        float4 w2 = *(const float4*)&WT[(k + 2) * D + tx * 4];
        float4 w3 = *(const float4*)&WT[(k + 3) * D + tx * 4];
        #pragma unroll
        for (int i = 0; i < 8; ++i) {
            float4 a4 = *(const float4*)&A[ty * 8 + i][k];
            acc[i][0] += a4.x * w0.x + a4.y * w1.x + a4.z * w2.x + a4.w * w3.x;
            acc[i][1] += a4.x * w0.y + a4.y * w1.y + a4.z * w2.y + a4.w * w3.y;
            acc[i][2] += a4.x * w0.z + a4.y * w1.z + a4.z * w2.z + a4.w * w3.z;
            acc[i][3] += a4.x * w0.w + a4.y * w1.w + a4.z * w2.w + a4.w * w3.w;
        }
    }
    #pragma unroll
    for (int i = 0; i < 8; ++i) {
        float4 v = make_float4(acc[i][0], acc[i][1], acc[i][2], acc[i][3]);
        *(float4*)&z[(size_t)(r0 + ty * 8 + i) * D + tx * 4] = v;
    }
}

// One wave per node: mean-aggregate z rows (incl. self loop), then the full
// hyperbolic epilogue: exp0(relu(mean)) -> geodesic blend with x -> proj.
// NOTE: xin/out may alias (layer 2 in-place) — no __restrict__ on them.
__global__ __launch_bounds__(256) void k_agg(const float* __restrict__ z,
                                             const float* xin,
                                             const int* __restrict__ off,
                                             const int* __restrict__ deg,
                                             const int* __restrict__ ssrc,
                                             float* out) {
    int wave = threadIdx.x >> 6, lane = threadIdx.x & 63;
    int node = blockIdx.x * 4 + wave;

    // self loop
    const float* zr = z + (size_t)node * D;
    float2 a = *(const float2*)(zr + 2 * lane);
    float ax = a.x, ay = a.y;

    int start = off[node];
    int dg = deg[node];
    for (int c = 0; c < dg; c += 64) {
        int m = min(64, dg - c);
        int sv = (lane < m) ? ssrc[start + c + lane] : 0;
        int j = 0;
        for (; j + 3 < m; j += 4) {
            int s0 = __shfl(sv, j), s1 = __shfl(sv, j + 1);
            int s2 = __shfl(sv, j + 2), s3 = __shfl(sv, j + 3);
            float2 v0 = *(const float2*)(z + (size_t)s0 * D + 2 * lane);
            float2 v1 = *(const float2*)(z + (size_t)s1 * D + 2 * lane);
            float2 v2 = *(const float2*)(z + (size_t)s2 * D + 2 * lane);
            float2 v3 = *(const float2*)(z + (size_t)s3 * D + 2 * lane);
            ax += v0.x + v1.x + v2.x + v3.x;
            ay += v0.y + v1.y + v2.y + v3.y;
        }
        for (; j < m; ++j) {
            int s = __shfl(sv, j);
            float2 v = *(const float2*)(z + (size_t)s * D + 2 * lane);
            ax += v.x;
            ay += v.y;
        }
    }

    float inv = 1.0f / (float)(dg + 1);
    float rx = fmaxf(ax * inv, 0.0f);
    float ry = fmaxf(ay * inv, 0.0f);

    // exp0(relu(mean))
    float ss = rx * rx + ry * ry;
    #pragma unroll
    for (int o = 1; o < 64; o <<= 1) ss += __shfl_xor(ss, o);
    float av = sqrtf(fmaxf(ss, EPSF * EPSF));
    float shf = sinhf(av) / av;
    float act0 = coshf(av);
    float asx = shf * rx, asy = shf * ry;

    // load x row
    const float* xr = xin + (size_t)node * DP;
    float x0 = xr[0];
    float xsx = xr[1 + 2 * lane];
    float xsy = xr[2 + 2 * lane];

    // alpha = max(-<x,act>_mink, 1+eps)
    float dot = asx * xsx + asy * xsy;
    #pragma unroll
    for (int o = 1; o < 64; o <<= 1) dot += __shfl_xor(dot, o);
    float mink = dot - act0 * x0;
    float alpha = fmaxf(-mink, 1.0f + EPSF);

    // u = act - alpha*x ; ||u||_mink
    float u0 = act0 - alpha * x0;
    float ux = asx - alpha * xsx;
    float uy = asy - alpha * xsy;
    float uss = ux * ux + uy * uy;
    #pragma unroll
    for (int o = 1; o < 64; o <<= 1) uss += __shfl_xor(uss, o);
    float uu = uss - u0 * u0;
    float un = sqrtf(fmaxf(uu, EPSF * EPSF));

    float d = acoshf(alpha);
    float a2 = 0.5f * d;  // beta * dist
    float ch2 = coshf(a2);
    float sh2 = sinhf(a2) / un;

    float ox = ch2 * xsx + sh2 * ux;
    float oy = ch2 * xsy + sh2 * uy;

    // proj: recompute time component
    float os = ox * ox + oy * oy;
    #pragma unroll
    for (int o = 1; o < 64; o <<= 1) os += __shfl_xor(os, o);
    float p0 = sqrtf(1.0f + os);

    float* orow = out + (size_t)node * DP;
    if (lane == 0) orow[0] = p0;
    orow[1 + 2 * lane] = ox;
    orow[2 + 2 * lane] = oy;
}

extern "C" void kernel_launch(void* const* d_in, const int* in_sizes, int n_in,
                              void* d_out, int out_size, void* d_ws, size_t ws_size,
                              hipStream_t stream) {
    const float* x  = (const float*)d_in[0];
    const int* ei   = (const int*)d_in[1];
    const float* W1 = (const float*)d_in[2];
    const float* b1 = (const float*)d_in[3];
    const float* W2 = (const float*)d_in[4];
    const float* b2 = (const float*)d_in[5];
    float* out = (float*)d_out;

    int n = in_sizes[0] / DP;      // 65536
    int E = in_sizes[1] / 2;       // 1048576
    const int* src = ei;
    const int* dst = ei + E;

    // workspace carve
    char* w = (char*)d_ws;
    float* z    = (float*)w; w += (size_t)n * D * sizeof(float);
    int* deg    = (int*)w;   w += (size_t)n * sizeof(int);
    int* off    = (int*)w;   w += (size_t)n * sizeof(int);
    int* cursor = (int*)w;   w += (size_t)n * sizeof(int);
    int* ssrc   = (int*)w;   w += (size_t)E * sizeof(int);
    float* WT1  = (float*)w; w += (size_t)D * D * sizeof(float);
    float* WT2  = (float*)w; w += (size_t)D * D * sizeof(float);

    int eb = (E + 255) / 256;

    // CSR build (shared by both layers)
    k_zero<<<(n + 255) / 256, 256, 0, stream>>>(deg, n);
    k_hist<<<eb, 256, 0, stream>>>(dst, E, deg);
    k_scan<<<1, 1024, 0, stream>>>(deg, off, cursor, n);
    k_scatter<<<eb, 256, 0, stream>>>(src, dst, E, cursor, ssrc);

    k_transpose<<<(D * D + 255) / 256, 256, 0, stream>>>(W1, WT1);
    k_transpose<<<(D * D + 255) / 256, 256, 0, stream>>>(W2, WT2);

    // layer 1
    k_gemm<<<n / 64, 256, 0, stream>>>(x, WT1, b1, z);
    k_agg<<<n / 4, 256, 0, stream>>>(z, x, off, deg, ssrc, out);

    // layer 2 (in-place on out for the node-wise part)
    k_gemm<<<n / 64, 256, 0, stream>>>(out, WT2, b2, z);
    k_agg<<<n / 4, 256, 0, stream>>>(z, out, off, deg, ssrc, out);
}

// Round 2
// 459.172 us; speedup vs baseline: 1.3378x; 1.3378x over previous
//
#include <hip/hip_runtime.h>
#include <hip/hip_bf16.h>
#include <hip/hip_fp16.h>
#include <math.h>

#define NN 65536
#define NE 1048576
#define D 128
#define DP 129
#define EPSF 1e-6f

__global__ void k_zero(int* p, int n) {
    int i = blockIdx.x * blockDim.x + threadIdx.x;
    if (i < n) p[i] = 0;
}

__global__ void k_hist(const int* __restrict__ dst, int E, int* __restrict__ deg) {
    int i = blockIdx.x * blockDim.x + threadIdx.x;
    if (i < E) atomicAdd(&deg[dst[i]], 1);
}

// --- parallel scan over deg[65536]: 3 small kernels, all coalesced ---
__global__ __launch_bounds__(256) void k_scan1(const int* __restrict__ deg,
                                               int* __restrict__ bsum) {
    __shared__ int sh[256];
    int t = threadIdx.x;
    sh[t] = deg[blockIdx.x * 256 + t];
    __syncthreads();
    for (int o = 128; o > 0; o >>= 1) {
        if (t < o) sh[t] += sh[t + o];
        __syncthreads();
    }
    if (t == 0) bsum[blockIdx.x] = sh[0];
}

__global__ __launch_bounds__(256) void k_scan2(const int* __restrict__ bsum,
                                               int* __restrict__ boff) {
    __shared__ int sh[256];
    int t = threadIdx.x;
    int v = bsum[t];
    sh[t] = v;
    __syncthreads();
    for (int o = 1; o < 256; o <<= 1) {
        int u = (t >= o) ? sh[t - o] : 0;
        __syncthreads();
        sh[t] += u;
        __syncthreads();
    }
    boff[t] = sh[t] - v;  // exclusive
}

__global__ __launch_bounds__(256) void k_scan3(const int* __restrict__ deg,
                                               const int* __restrict__ boff,
                                               int* __restrict__ off,
                                               int* __restrict__ cursor) {
    __shared__ int sh[256];
    int t = threadIdx.x;
    int i = blockIdx.x * 256 + t;
    int v = deg[i];
    sh[t] = v;
    __syncthreads();
    for (int o = 1; o < 256; o <<= 1) {
        int u = (t >= o) ? sh[t - o] : 0;
        __syncthreads();
        sh[t] += u;
        __syncthreads();
    }
    int ex = sh[t] - v + boff[blockIdx.x];
    off[i] = ex;
    cursor[i] = ex;
}

__global__ void k_scatter(const int* __restrict__ src, const int* __restrict__ dst,
                          int E, int* __restrict__ cursor, int* __restrict__ ssrc) {
    int i = blockIdx.x * blockDim.x + threadIdx.x;
    if (i < E) {
        int d = dst[i];
        int p = atomicAdd(&cursor[d], 1);
        ssrc[p] = src[i];
    }
}

__global__ void k_transpose(const float* __restrict__ W, float* __restrict__ WT) {
    int i = blockIdx.x * blockDim.x + threadIdx.x;  // 16384
    if (i < D * D) {
        int k = i >> 7, j = i & 127;
        WT[i] = W[j * D + k];  // WT[k][j] = W[j][k]
    }
}

// z[r][j] = sum_k log0(x[r])[k] * W[j][k] + b[j], stored as f16
__global__ __launch_bounds__(256) void k_gemm(const float* __restrict__ x,
                                              const float* __restrict__ WT,
                                              const float* __restrict__ b,
                                              __half* __restrict__ z) {
    __shared__ float A[64][132];  // pitch 132 to kill bank conflicts
    int t = threadIdx.x;
    int wave = t >> 6, lane = t & 63;
    int r0 = blockIdx.x * 64;

    // phase 1: compute log0 rows into LDS
    for (int rl = wave; rl < 64; rl += 4) {
        const float* xr = x + (size_t)(r0 + rl) * DP;
        float x0 = xr[0];
        float a0 = xr[1 + lane];
        float a1 = xr[1 + 64 + lane];
        float ss = a0 * a0 + a1 * a1;
        #pragma unroll
        for (int o = 1; o < 64; o <<= 1) ss += __shfl_xor(ss, o);
        float xn = sqrtf(fmaxf(ss, EPSF * EPSF));
        float theta = acoshf(fmaxf(x0, 1.0f + EPSF));
        float f = theta / xn;
        A[rl][lane] = f * a0;
        A[rl][64 + lane] = f * a1;
    }
    __syncthreads();

    // phase 2: 256 threads; thread = (ty,tx): rows ty*8..+7, cols tx*4..+3
    int tx = t & 31, ty = t >> 5;
    float acc[8][4];
    float4 bb = *(const float4*)&b[tx * 4];
    #pragma unroll
    for (int i = 0; i < 8; ++i) {
        acc[i][0] = bb.x; acc[i][1] = bb.y; acc[i][2] = bb.z; acc[i][3] = bb.w;
    }
    #pragma unroll 4
    for (int k = 0; k < D; k += 4) {
        float4 w0 = *(const float4*)&WT[(k + 0) * D + tx * 4];
        float4 w1 = *(const float4*)&WT[(k + 1) * D + tx * 4];
        float4 w2 = *(const float4*)&WT[(k + 2) * D + tx * 4];
        float4 w3 = *(const float4*)&WT[(k + 3) * D + tx * 4];
        #pragma unroll
        for (int i = 0; i < 8; ++i) {
            float4 a4 = *(const float4*)&A[ty * 8 + i][k];
            acc[i][0] += a4.x * w0.x + a4.y * w1.x + a4.z * w2.x + a4.w * w3.x;
            acc[i][1] += a4.x * w0.y + a4.y * w1.y + a4.z * w2.y + a4.w * w3.y;
            acc[i][2] += a4.x * w0.z + a4.y * w1.z + a4.z * w2.z + a4.w * w3.z;
            acc[i][3] += a4.x * w0.w + a4.y * w1.w + a4.z * w2.w + a4.w * w3.w;
        }
    }
    #pragma unroll
    for (int i = 0; i < 8; ++i) {
        __half2 h0 = __floats2half2_rn(acc[i][0], acc[i][1]);
        __half2 h1 = __floats2half2_rn(acc[i][2], acc[i][3]);
        __half2* zp = (__half2*)(z + (size_t)(r0 + ty * 8 + i) * D + tx * 4);
        zp[0] = h0;
        zp[1] = h1;
    }
}

// One wave per node: mean-aggregate z rows (incl. self loop), then the full
// hyperbolic epilogue: exp0(relu(mean)) -> geodesic blend with x -> proj.
// NOTE: xin/out may alias (layer 2 in-place) — no __restrict__ on them.
__global__ __launch_bounds__(256) void k_agg(const __half* __restrict__ z,
                                             const float* xin,
                                             const int* __restrict__ off,
                                             const int* __restrict__ deg,
                                             const int* __restrict__ ssrc,
                                             float* out) {
    int wave = threadIdx.x >> 6, lane = threadIdx.x & 63;
    int node = blockIdx.x * 4 + wave;

    // self loop
    float2 a = __half22float2(*((const __half2*)(z + (size_t)node * D) + lane));
    float ax = a.x, ay = a.y;

    int start = off[node];
    int dg = deg[node];
    for (int c = 0; c < dg; c += 64) {
        int m = min(64, dg - c);
        int sv = (lane < m) ? ssrc[start + c + lane] : 0;
        int j = 0;
        for (; j + 3 < m; j += 4) {
            int s0 = __shfl(sv, j), s1 = __shfl(sv, j + 1);
            int s2 = __shfl(sv, j + 2), s3 = __shfl(sv, j + 3);
            float2 v0 = __half22float2(*((const __half2*)(z + (size_t)s0 * D) + lane));
            float2 v1 = __half22float2(*((const __half2*)(z + (size_t)s1 * D) + lane));
            float2 v2 = __half22float2(*((const __half2*)(z + (size_t)s2 * D) + lane));
            float2 v3 = __half22float2(*((const __half2*)(z + (size_t)s3 * D) + lane));
            ax += v0.x + v1.x + v2.x + v3.x;
            ay += v0.y + v1.y + v2.y + v3.y;
        }
        for (; j < m; ++j) {
            int s = __shfl(sv, j);
            float2 v = __half22float2(*((const __half2*)(z + (size_t)s * D) + lane));
            ax += v.x;
            ay += v.y;
        }
    }

    float inv = 1.0f / (float)(dg + 1);
    float rx = fmaxf(ax * inv, 0.0f);
    float ry = fmaxf(ay * inv, 0.0f);

    // exp0(relu(mean))
    float ss = rx * rx + ry * ry;
    #pragma unroll
    for (int o = 1; o < 64; o <<= 1) ss += __shfl_xor(ss, o);
    float av = sqrtf(fmaxf(ss, EPSF * EPSF));
    float shf = sinhf(av) / av;
    float act0 = coshf(av);
    float asx = shf * rx, asy = shf * ry;

    // load x row
    const float* xr = xin + (size_t)node * DP;
    float x0 = xr[0];
    float xsx = xr[1 + 2 * lane];
    float xsy = xr[2 + 2 * lane];

    // alpha = max(-<x,act>_mink, 1+eps)
    float dot = asx * xsx + asy * xsy;
    #pragma unroll
    for (int o = 1; o < 64; o <<= 1) dot += __shfl_xor(dot, o);
    float mink = dot - act0 * x0;
    float alpha = fmaxf(-mink, 1.0f + EPSF);

    // u = act - alpha*x ; ||u||_mink
    float u0 = act0 - alpha * x0;
    float ux = asx - alpha * xsx;
    float uy = asy - alpha * xsy;
    float uss = ux * ux + uy * uy;
    #pragma unroll
    for (int o = 1; o < 64; o <<= 1) uss += __shfl_xor(uss, o);
    float uu = uss - u0 * u0;
    float un = sqrtf(fmaxf(uu, EPSF * EPSF));

    float d = acoshf(alpha);
    float a2 = 0.5f * d;  // beta * dist
    float ch2 = coshf(a2);
    float sh2 = sinhf(a2) / un;

    float ox = ch2 * xsx + sh2 * ux;
    float oy = ch2 * xsy + sh2 * uy;

    // proj: recompute time component
    float os = ox * ox + oy * oy;
    #pragma unroll
    for (int o = 1; o < 64; o <<= 1) os += __shfl_xor(os, o);
    float p0 = sqrtf(1.0f + os);

    float* orow = out + (size_t)node * DP;
    if (lane == 0) orow[0] = p0;
    orow[1 + 2 * lane] = ox;
    orow[2 + 2 * lane] = oy;
}

extern "C" void kernel_launch(void* const* d_in, const int* in_sizes, int n_in,
                              void* d_out, int out_size, void* d_ws, size_t ws_size,
                              hipStream_t stream) {
    const float* x  = (const float*)d_in[0];
    const int* ei   = (const int*)d_in[1];
    const float* W1 = (const float*)d_in[2];
    const float* b1 = (const float*)d_in[3];
    const float* W2 = (const float*)d_in[4];
    const float* b2 = (const float*)d_in[5];
    float* out = (float*)d_out;

    int n = in_sizes[0] / DP;      // 65536
    int E = in_sizes[1] / 2;       // 1048576
    const int* src = ei;
    const int* dst = ei + E;

    // workspace carve
    char* w = (char*)d_ws;
    __half* z   = (__half*)w; w += (size_t)n * D * sizeof(__half);
    int* deg    = (int*)w;   w += (size_t)n * sizeof(int);
    int* off    = (int*)w;   w += (size_t)n * sizeof(int);
    int* cursor = (int*)w;   w += (size_t)n * sizeof(int);
    int* ssrc   = (int*)w;   w += (size_t)E * sizeof(int);
    float* WT1  = (float*)w; w += (size_t)D * D * sizeof(float);
    float* WT2  = (float*)w; w += (size_t)D * D * sizeof(float);
    int* bsum   = (int*)w;   w += 256 * sizeof(int);
    int* boff   = (int*)w;   w += 256 * sizeof(int);

    int eb = (E + 255) / 256;
    int nb = n / 256;  // 256

    // CSR build (shared by both layers)
    k_zero<<<(n + 255) / 256, 256, 0, stream>>>(deg, n);
    k_hist<<<eb, 256, 0, stream>>>(dst, E, deg);
    k_scan1<<<nb, 256, 0, stream>>>(deg, bsum);
    k_scan2<<<1, 256, 0, stream>>>(bsum, boff);
    k_scan3<<<nb, 256, 0, stream>>>(deg, boff, off, cursor);
    k_scatter<<<eb, 256, 0, stream>>>(src, dst, E, cursor, ssrc);

    k_transpose<<<(D * D + 255) / 256, 256, 0, stream>>>(W1, WT1);
    k_transpose<<<(D * D + 255) / 256, 256, 0, stream>>>(W2, WT2);

    // layer 1
    k_gemm<<<n / 64, 256, 0, stream>>>(x, WT1, b1, z);
    k_agg<<<n / 4, 256, 0, stream>>>(z, x, off, deg, ssrc, out);

    // layer 2 (in-place on out for the node-wise part)
    k_gemm<<<n / 64, 256, 0, stream>>>(out, WT2, b2, z);
    k_agg<<<n / 4, 256, 0, stream>>>(z, out, off, deg, ssrc, out);
}

// Round 4
// 393.817 us; speedup vs baseline: 1.5598x; 1.1660x over previous
//
#include <hip/hip_runtime.h>
#include <hip/hip_bf16.h>
#include <hip/hip_fp16.h>
#include <math.h>

#define NN 65536
#define NE 1048576
#define D 128
#define DP 129
#define EPSF 1e-6f

__device__ __forceinline__ float frcp(float x) { return __builtin_amdgcn_rcpf(x); }
__device__ __forceinline__ float fsqrt(float x) { return __builtin_amdgcn_sqrtf(x); }
__device__ __forceinline__ float facosh(float x) {
    // x >= 1+eps; log(x + sqrt(x^2-1))
    return __logf(x + fsqrt(fmaxf(x * x - 1.0f, 0.0f)));
}

__global__ void k_zero(int* p, int n) {
    int i = blockIdx.x * blockDim.x + threadIdx.x;
    if (i < n) p[i] = 0;
}

__global__ void k_hist(const int* __restrict__ dst, int E, int* __restrict__ deg) {
    int i = blockIdx.x * blockDim.x + threadIdx.x;
    if (i < E) atomicAdd(&deg[dst[i]], 1);
}

// --- parallel scan over deg[65536]: 3 small kernels, all coalesced ---
__global__ __launch_bounds__(256) void k_scan1(const int* __restrict__ deg,
                                               int* __restrict__ bsum) {
    __shared__ int sh[256];
    int t = threadIdx.x;
    sh[t] = deg[blockIdx.x * 256 + t];
    __syncthreads();
    for (int o = 128; o > 0; o >>= 1) {
        if (t < o) sh[t] += sh[t + o];
        __syncthreads();
    }
    if (t == 0) bsum[blockIdx.x] = sh[0];
}

__global__ __launch_bounds__(256) void k_scan2(const int* __restrict__ bsum,
                                               int* __restrict__ boff) {
    __shared__ int sh[256];
    int t = threadIdx.x;
    int v = bsum[t];
    sh[t] = v;
    __syncthreads();
    for (int o = 1; o < 256; o <<= 1) {
        int u = (t >= o) ? sh[t - o] : 0;
        __syncthreads();
        sh[t] += u;
        __syncthreads();
    }
    boff[t] = sh[t] - v;  // exclusive
}

__global__ __launch_bounds__(256) void k_scan3(const int* __restrict__ deg,
                                               const int* __restrict__ boff,
                                               int* __restrict__ off,
                                               int* __restrict__ cursor) {
    __shared__ int sh[256];
    int t = threadIdx.x;
    int i = blockIdx.x * 256 + t;
    int v = deg[i];
    sh[t] = v;
    __syncthreads();
    for (int o = 1; o < 256; o <<= 1) {
        int u = (t >= o) ? sh[t - o] : 0;
        __syncthreads();
        sh[t] += u;
        __syncthreads();
    }
    int ex = sh[t] - v + boff[blockIdx.x];
    off[i] = ex;
    cursor[i] = ex;
}

__global__ void k_scatter(const int* __restrict__ src, const int* __restrict__ dst,
                          int E, int* __restrict__ cursor, int* __restrict__ ssrc) {
    int i = blockIdx.x * blockDim.x + threadIdx.x;
    if (i < E) {
        int d = dst[i];
        int p = atomicAdd(&cursor[d], 1);
        ssrc[p] = src[i];
    }
}

__global__ void k_transpose(const float* __restrict__ W, float* __restrict__ WT) {
    int i = blockIdx.x * blockDim.x + threadIdx.x;  // 16384
    if (i < D * D) {
        int k = i >> 7, j = i & 127;
        WT[i] = W[j * D + k];  // WT[k][j] = W[j][k]
    }
}

// z[r][j] = sum_k log0(x[r])[k] * W[j][k] + b[j], stored as f16
__global__ __launch_bounds__(256) void k_gemm(const float* __restrict__ x,
                                              const float* __restrict__ WT,
                                              const float* __restrict__ b,
                                              __half* __restrict__ z) {
    __shared__ float A[64][132];  // pitch 132 to kill bank conflicts
    int t = threadIdx.x;
    int wave = t >> 6, lane = t & 63;
    int r0 = blockIdx.x * 64;

    // phase 1: compute log0 rows into LDS
    for (int rl = wave; rl < 64; rl += 4) {
        const float* xr = x + (size_t)(r0 + rl) * DP;
        float x0 = xr[0];
        float a0 = xr[1 + lane];
        float a1 = xr[1 + 64 + lane];
        float ss = a0 * a0 + a1 * a1;
        #pragma unroll
        for (int o = 1; o < 64; o <<= 1) ss += __shfl_xor(ss, o);
        float xn = fsqrt(fmaxf(ss, EPSF * EPSF));
        float theta = facosh(fmaxf(x0, 1.0f + EPSF));
        float f = theta * frcp(xn);
        A[rl][lane] = f * a0;
        A[rl][64 + lane] = f * a1;
    }
    __syncthreads();

    // phase 2: 256 threads; thread = (ty,tx): rows ty*8..+7, cols tx*4..+3
    int tx = t & 31, ty = t >> 5;
    float acc[8][4];
    float4 bb = *(const float4*)&b[tx * 4];
    #pragma unroll
    for (int i = 0; i < 8; ++i) {
        acc[i][0] = bb.x; acc[i][1] = bb.y; acc[i][2] = bb.z; acc[i][3] = bb.w;
    }
    #pragma unroll 4
    for (int k = 0; k < D; k += 4) {
        float4 w0 = *(const float4*)&WT[(k + 0) * D + tx * 4];
        float4 w1 = *(const float4*)&WT[(k + 1) * D + tx * 4];
        float4 w2 = *(const float4*)&WT[(k + 2) * D + tx * 4];
        float4 w3 = *(const float4*)&WT[(k + 3) * D + tx * 4];
        #pragma unroll
        for (int i = 0; i < 8; ++i) {
            float4 a4 = *(const float4*)&A[ty * 8 + i][k];
            acc[i][0] += a4.x * w0.x + a4.y * w1.x + a4.z * w2.x + a4.w * w3.x;
            acc[i][1] += a4.x * w0.y + a4.y * w1.y + a4.z * w2.y + a4.w * w3.y;
            acc[i][2] += a4.x * w0.z + a4.y * w1.z + a4.z * w2.z + a4.w * w3.z;
            acc[i][3] += a4.x * w0.w + a4.y * w1.w + a4.z * w2.w + a4.w * w3.w;
        }
    }
    #pragma unroll
    for (int i = 0; i < 8; ++i) {
        __half2 h0 = __floats2half2_rn(acc[i][0], acc[i][1]);
        __half2 h1 = __floats2half2_rn(acc[i][2], acc[i][3]);
        __half2* zp = (__half2*)(z + (size_t)(r0 + ty * 8 + i) * D + tx * 4);
        zp[0] = h0;
        zp[1] = h1;
    }
}

// One wave per node. Wave-uniform values (node, off, deg, edge ids) are pinned
// to SGPRs so the gather is: SGPR row base + constant lane offset -> saddr
// global_load, 2 cvt, 2 add per edge. Epilogue uses shared-exp sinh/cosh.
__global__ __launch_bounds__(256) void k_agg(const __half* __restrict__ z,
                                             const float* xin,
                                             const int* __restrict__ off,
                                             const int* __restrict__ deg,
                                             const int* __restrict__ ssrc,
                                             float* out) {
    int wave = threadIdx.x >> 6, lane = threadIdx.x & 63;
    int node = __builtin_amdgcn_readfirstlane(blockIdx.x * 4 + wave);

    const __half2* zl = (const __half2*)z;

    // self loop
    float2 a = __half22float2(zl[(size_t)node * 64 + lane]);
    float ax0 = a.x, ay0 = a.y, ax1 = 0.f, ay1 = 0.f;

    int start = __builtin_amdgcn_readfirstlane(off[node]);
    int dg = __builtin_amdgcn_readfirstlane(deg[node]);

    for (int c = 0; c < dg; c += 64) {
        int rem = dg - c;
        int m = rem < 64 ? rem : 64;
        int sv = ssrc[start + c + lane];  // ssrc padded by 64 -> no guard
        int j = 0;
        for (; j + 7 < m; j += 8) {
            int s0 = __builtin_amdgcn_readlane(sv, j + 0);
            int s1 = __builtin_amdgcn_readlane(sv, j + 1);
            int s2 = __builtin_amdgcn_readlane(sv, j + 2);
            int s3 = __builtin_amdgcn_readlane(sv, j + 3);
            int s4 = __builtin_amdgcn_readlane(sv, j + 4);
            int s5 = __builtin_amdgcn_readlane(sv, j + 5);
            int s6 = __builtin_amdgcn_readlane(sv, j + 6);
            int s7 = __builtin_amdgcn_readlane(sv, j + 7);
            float2 v0 = __half22float2(zl[(size_t)s0 * 64 + lane]);
            float2 v1 = __half22float2(zl[(size_t)s1 * 64 + lane]);
            float2 v2 = __half22float2(zl[(size_t)s2 * 64 + lane]);
            float2 v3 = __half22float2(zl[(size_t)s3 * 64 + lane]);
            float2 v4 = __half22float2(zl[(size_t)s4 * 64 + lane]);
            float2 v5 = __half22float2(zl[(size_t)s5 * 64 + lane]);
            float2 v6 = __half22float2(zl[(size_t)s6 * 64 + lane]);
            float2 v7 = __half22float2(zl[(size_t)s7 * 64 + lane]);
            ax0 += v0.x + v1.x + v2.x + v3.x;
            ay0 += v0.y + v1.y + v2.y + v3.y;
            ax1 += v4.x + v5.x + v6.x + v7.x;
            ay1 += v4.y + v5.y + v6.y + v7.y;
        }
        for (; j < m; ++j) {
            int s = __builtin_amdgcn_readlane(sv, j);
            float2 v = __half22float2(zl[(size_t)s * 64 + lane]);
            ax0 += v.x;
            ay0 += v.y;
        }
    }
    float ax = ax0 + ax1, ay = ay0 + ay1;

    float inv = frcp((float)(dg + 1));
    float rx = fmaxf(ax * inv, 0.0f);
    float ry = fmaxf(ay * inv, 0.0f);

    // exp0(relu(mean))
    float ss = rx * rx + ry * ry;
    #pragma unroll
    for (int o = 1; o < 64; o <<= 1) ss += __shfl_xor(ss, o);
    float av = fsqrt(fmaxf(ss, EPSF * EPSF));
    float t1 = __expf(av);
    float t1i = frcp(t1);
    float shf = 0.5f * (t1 - t1i) * frcp(av);
    float act0 = 0.5f * (t1 + t1i);
    float asx = shf * rx, asy = shf * ry;

    // load x row
    const float* xr = xin + (size_t)node * DP;
    float x0 = xr[0];
    float xsx = xr[1 + 2 * lane];
    float xsy = xr[2 + 2 * lane];

    // alpha = max(-<x,act>_mink, 1+eps)
    float dot = asx * xsx + asy * xsy;
    #pragma unroll
    for (int o = 1; o < 64; o <<= 1) dot += __shfl_xor(dot, o);
    float mink = dot - act0 * x0;
    float alpha = fmaxf(-mink, 1.0f + EPSF);

    // u = act - alpha*x ; ||u||_mink
    float u0 = act0 - alpha * x0;
    float ux = asx - alpha * xsx;
    float uy = asy - alpha * xsy;
    float uss = ux * ux + uy * uy;
    #pragma unroll
    for (int o = 1; o < 64; o <<= 1) uss += __shfl_xor(uss, o);
    float uu = uss - u0 * u0;
    float un = fsqrt(fmaxf(uu, EPSF * EPSF));

    float d = facosh(alpha);
    float a2 = 0.5f * d;  // beta * dist
    float t2 = __expf(a2);
    float t2i = frcp(t2);
    float ch2 = 0.5f * (t2 + t2i);
    float sh2 = 0.5f * (t2 - t2i) * frcp(un);

    float ox = ch2 * xsx + sh2 * ux;
    float oy = ch2 * xsy + sh2 * uy;

    // proj: recompute time component
    float os = ox * ox + oy * oy;
    #pragma unroll
    for (int o = 1; o < 64; o <<= 1) os += __shfl_xor(os, o);
    float p0 = fsqrt(1.0f + os);

    float* orow = out + (size_t)node * DP;
    if (lane == 0) orow[0] = p0;
    orow[1 + 2 * lane] = ox;
    orow[2 + 2 * lane] = oy;
}

extern "C" void kernel_launch(void* const* d_in, const int* in_sizes, int n_in,
                              void* d_out, int out_size, void* d_ws, size_t ws_size,
                              hipStream_t stream) {
    const float* x  = (const float*)d_in[0];
    const int* ei   = (const int*)d_in[1];
    const float* W1 = (const float*)d_in[2];
    const float* b1 = (const float*)d_in[3];
    const float* W2 = (const float*)d_in[4];
    const float* b2 = (const float*)d_in[5];
    float* out = (float*)d_out;

    int n = in_sizes[0] / DP;      // 65536
    int E = in_sizes[1] / 2;       // 1048576
    const int* src = ei;
    const int* dst = ei + E;

    // workspace carve
    char* w = (char*)d_ws;
    __half* z   = (__half*)w; w += (size_t)n * D * sizeof(__half);
    int* deg    = (int*)w;   w += (size_t)n * sizeof(int);
    int* off    = (int*)w;   w += (size_t)n * sizeof(int);
    int* cursor = (int*)w;   w += (size_t)n * sizeof(int);
    int* ssrc   = (int*)w;   w += ((size_t)E + 64) * sizeof(int);  // +64 pad
    float* WT1  = (float*)w; w += (size_t)D * D * sizeof(float);
    float* WT2  = (float*)w; w += (size_t)D * D * sizeof(float);
    int* bsum   = (int*)w;   w += 256 * sizeof(int);
    int* boff   = (int*)w;   w += 256 * sizeof(int);

    int eb = (E + 255) / 256;
    int nb = n / 256;  // 256

    // CSR build (shared by both layers)
    k_zero<<<(n + 255) / 256, 256, 0, stream>>>(deg, n);
    k_hist<<<eb, 256, 0, stream>>>(dst, E, deg);
    k_scan1<<<nb, 256, 0, stream>>>(deg, bsum);
    k_scan2<<<1, 256, 0, stream>>>(bsum, boff);
    k_scan3<<<nb, 256, 0, stream>>>(deg, boff, off, cursor);
    k_scatter<<<eb, 256, 0, stream>>>(src, dst, E, cursor, ssrc);

    k_transpose<<<(D * D + 255) / 256, 256, 0, stream>>>(W1, WT1);
    k_transpose<<<(D * D + 255) / 256, 256, 0, stream>>>(W2, WT2);

    // layer 1
    k_gemm<<<n / 64, 256, 0, stream>>>(x, WT1, b1, z);
    k_agg<<<n / 4, 256, 0, stream>>>(z, x, off, deg, ssrc, out);

    // layer 2 (in-place on out for the node-wise part)
    k_gemm<<<n / 64, 256, 0, stream>>>(out, WT2, b2, z);
    k_agg<<<n / 4, 256, 0, stream>>>(z, out, off, deg, ssrc, out);
}

// Round 8
// 323.255 us; speedup vs baseline: 1.9002x; 1.2183x over previous
//
#include <hip/hip_runtime.h>
#include <hip/hip_bf16.h>
#include <hip/hip_fp16.h>
#include <math.h>

#define NN 65536
#define NE 1048576
#define D 128
#define DP 129
#define EPSF 1e-6f
#define TILE 4096  // edges per block in k_bhist / k_bsplit (16 per thread)

__device__ __forceinline__ float frcp(float x) { return __builtin_amdgcn_rcpf(x); }
__device__ __forceinline__ float fsqrt(float x) { return __builtin_amdgcn_sqrtf(x); }
__device__ __forceinline__ float facosh(float x) {
    // x >= 1+eps; log(x + sqrt(x^2-1))
    return __logf(x + fsqrt(fmaxf(x * x - 1.0f, 0.0f)));
}

// ---- CSR build: two-level multisplit (bucket = dst>>8, 256 buckets) ----

__global__ __launch_bounds__(256) void k_bzero(int* __restrict__ bcnt) {
    bcnt[threadIdx.x] = 0;
}

__global__ __launch_bounds__(256) void k_bhist(const int* __restrict__ dst, int E,
                                               int* __restrict__ bcnt) {
    __shared__ int lh[256];
    int t = threadIdx.x;
    lh[t] = 0;
    __syncthreads();
    int base = blockIdx.x * TILE;
    #pragma unroll
    for (int k = 0; k < 16; ++k) {
        int i = base + k * 256 + t;
        if (i < E) atomicAdd(&lh[dst[i] >> 8], 1);
    }
    __syncthreads();
    if (lh[t]) atomicAdd(&bcnt[t], lh[t]);
}

__global__ __launch_bounds__(256) void k_bscan(const int* __restrict__ bcnt,
                                               int* __restrict__ bbase,
                                               int* __restrict__ bcur) {
    __shared__ int sh[256];
    int t = threadIdx.x;
    int v = bcnt[t];
    sh[t] = v;
    __syncthreads();
    for (int o = 1; o < 256; o <<= 1) {
        int u = (t >= o) ? sh[t - o] : 0;
        __syncthreads();
        sh[t] += u;
        __syncthreads();
    }
    int ex = sh[t] - v;
    bbase[t] = ex;
    bcur[t] = ex;
}

// pack (dst&255)<<16 | src  (src < 65536)
__global__ __launch_bounds__(256) void k_bsplit(const int* __restrict__ src,
                                                const int* __restrict__ dst, int E,
                                                int* __restrict__ bcur,
                                                unsigned int* __restrict__ ebuf) {
    __shared__ int lh[256];
    __shared__ int gres[256];
    int t = threadIdx.x;
    lh[t] = 0;
    __syncthreads();
    int base = blockIdx.x * TILE;
    unsigned int pk[16];
    int bk[16], rk[16];
    #pragma unroll
    for (int k = 0; k < 16; ++k) {
        int i = base + k * 256 + t;
        if (i < E) {
            int d = dst[i];
            int b = d >> 8;
            bk[k] = b;
            pk[k] = ((unsigned)(d & 255) << 16) | (unsigned)src[i];
            rk[k] = atomicAdd(&lh[b], 1);
        } else {
            bk[k] = -1; rk[k] = 0; pk[k] = 0;
        }
    }
    __syncthreads();
    gres[t] = lh[t] ? atomicAdd(&bcur[t], lh[t]) : 0;
    __syncthreads();
    #pragma unroll
    for (int k = 0; k < 16; ++k) {
        if (bk[k] >= 0) ebuf[gres[bk[k]] + rk[k]] = pk[k];
    }
}

// one block per bucket: per-node hist/scan -> deg/off, then local scatter of src
__global__ __launch_bounds__(256) void k_csr(const unsigned int* __restrict__ ebuf,
                                             const int* __restrict__ bcnt,
                                             const int* __restrict__ bbase,
                                             int* __restrict__ deg,
                                             int* __restrict__ off,
                                             int* __restrict__ ssrc) {
    __shared__ int lh[256];
    __shared__ int sc[256];
    __shared__ int lcur[256];
    int t = threadIdx.x;
    int b = blockIdx.x;
    int start = bbase[b];
    int cnt = bcnt[b];
    lh[t] = 0;
    __syncthreads();
    for (int i = t; i < cnt; i += 256) {
        unsigned int e = ebuf[start + i];
        atomicAdd(&lh[e >> 16], 1);
    }
    __syncthreads();
    int v = lh[t];
    sc[t] = v;
    __syncthreads();
    for (int o = 1; o < 256; o <<= 1) {
        int u = (t >= o) ? sc[t - o] : 0;
        __syncthreads();
        sc[t] += u;
        __syncthreads();
    }
    int ex = sc[t] - v;
    int node = (b << 8) + t;
    deg[node] = v;
    off[node] = start + ex;
    lcur[t] = ex;
    __syncthreads();
    for (int i = t; i < cnt; i += 256) {
        unsigned int e = ebuf[start + i];
        int d = e >> 16;
        int r = atomicAdd(&lcur[d], 1);
        ssrc[start + r] = (int)(e & 0xFFFFu);
    }
}

// ---- dense kernels ----

__global__ void k_transpose(const float* __restrict__ W, float* __restrict__ WT) {
    int i = blockIdx.x * blockDim.x + threadIdx.x;  // 16384
    if (i < D * D) {
        int k = i >> 7, j = i & 127;
        WT[i] = W[j * D + k];  // WT[k][j] = W[j][k]
    }
}

// z[r][j] = sum_k log0(x[r])[k] * W[j][k] + b[j], stored as f16
__global__ __launch_bounds__(256) void k_gemm(const float* __restrict__ x,
                                              const float* __restrict__ WT,
                                              const float* __restrict__ b,
                                              __half* __restrict__ z) {
    __shared__ float A[64][132];  // pitch 132 to kill bank conflicts
    int t = threadIdx.x;
    int wave = t >> 6, lane = t & 63;
    int r0 = blockIdx.x * 64;

    // phase 1: compute log0 rows into LDS
    for (int rl = wave; rl < 64; rl += 4) {
        const float* xr = x + (size_t)(r0 + rl) * DP;
        float x0 = xr[0];
        float a0 = xr[1 + lane];
        float a1 = xr[1 + 64 + lane];
        float ss = a0 * a0 + a1 * a1;
        #pragma unroll
        for (int o = 1; o < 64; o <<= 1) ss += __shfl_xor(ss, o);
        float xn = fsqrt(fmaxf(ss, EPSF * EPSF));
        float theta = facosh(fmaxf(x0, 1.0f + EPSF));
        float f = theta * frcp(xn);
        A[rl][lane] = f * a0;
        A[rl][64 + lane] = f * a1;
    }
    __syncthreads();

    // phase 2: 256 threads; thread = (ty,tx): rows ty*8..+7, cols tx*4..+3
    int tx = t & 31, ty = t >> 5;
    float acc[8][4];
    float4 bb = *(const float4*)&b[tx * 4];
    #pragma unroll
    for (int i = 0; i < 8; ++i) {
        acc[i][0] = bb.x; acc[i][1] = bb.y; acc[i][2] = bb.z; acc[i][3] = bb.w;
    }
    #pragma unroll 4
    for (int k = 0; k < D; k += 4) {
        float4 w0 = *(const float4*)&WT[(k + 0) * D + tx * 4];
        float4 w1 = *(const float4*)&WT[(k + 1) * D + tx * 4];
        float4 w2 = *(const float4*)&WT[(k + 2) * D + tx * 4];
        float4 w3 = *(const float4*)&WT[(k + 3) * D + tx * 4];
        #pragma unroll
        for (int i = 0; i < 8; ++i) {
            float4 a4 = *(const float4*)&A[ty * 8 + i][k];
            acc[i][0] += a4.x * w0.x + a4.y * w1.x + a4.z * w2.x + a4.w * w3.x;
            acc[i][1] += a4.x * w0.y + a4.y * w1.y + a4.z * w2.y + a4.w * w3.y;
            acc[i][2] += a4.x * w0.z + a4.y * w1.z + a4.z * w2.z + a4.w * w3.z;
            acc[i][3] += a4.x * w0.w + a4.y * w1.w + a4.z * w2.w + a4.w * w3.w;
        }
    }
    #pragma unroll
    for (int i = 0; i < 8; ++i) {
        __half2 h0 = __floats2half2_rn(acc[i][0], acc[i][1]);
        __half2 h1 = __floats2half2_rn(acc[i][2], acc[i][3]);
        __half2* zp = (__half2*)(z + (size_t)(r0 + ty * 8 + i) * D + tx * 4);
        zp[0] = h0;
        zp[1] = h1;
    }
}

// One wave per node. Wave-uniform values (node, off, deg, edge ids) pinned to
// SGPRs: gather is SGPR row base + lane offset. Epilogue: shared-exp sinh/cosh.
__global__ __launch_bounds__(256) void k_agg(const __half* __restrict__ z,
                                             const float* xin,
                                             const int* __restrict__ off,
                                             const int* __restrict__ deg,
                                             const int* __restrict__ ssrc,
                                             float* out) {
    int wave = threadIdx.x >> 6, lane = threadIdx.x & 63;
    int node = __builtin_amdgcn_readfirstlane(blockIdx.x * 4 + wave);

    const __half2* zl = (const __half2*)z;

    // self loop
    float2 a = __half22float2(zl[(size_t)node * 64 + lane]);
    float ax0 = a.x, ay0 = a.y, ax1 = 0.f, ay1 = 0.f;

    int start = __builtin_amdgcn_readfirstlane(off[node]);
    int dg = __builtin_amdgcn_readfirstlane(deg[node]);

    for (int c = 0; c < dg; c += 64) {
        int rem = dg - c;
        int m = rem < 64 ? rem : 64;
        int sv = ssrc[start + c + lane];  // ssrc padded by 64 -> no guard
        int j = 0;
        for (; j + 7 < m; j += 8) {
            int s0 = __builtin_amdgcn_readlane(sv, j + 0);
            int s1 = __builtin_amdgcn_readlane(sv, j + 1);
            int s2 = __builtin_amdgcn_readlane(sv, j + 2);
            int s3 = __builtin_amdgcn_readlane(sv, j + 3);
            int s4 = __builtin_amdgcn_readlane(sv, j + 4);
            int s5 = __builtin_amdgcn_readlane(sv, j + 5);
            int s6 = __builtin_amdgcn_readlane(sv, j + 6);
            int s7 = __builtin_amdgcn_readlane(sv, j + 7);
            float2 v0 = __half22float2(zl[(size_t)s0 * 64 + lane]);
            float2 v1 = __half22float2(zl[(size_t)s1 * 64 + lane]);
            float2 v2 = __half22float2(zl[(size_t)s2 * 64 + lane]);
            float2 v3 = __half22float2(zl[(size_t)s3 * 64 + lane]);
            float2 v4 = __half22float2(zl[(size_t)s4 * 64 + lane]);
            float2 v5 = __half22float2(zl[(size_t)s5 * 64 + lane]);
            float2 v6 = __half22float2(zl[(size_t)s6 * 64 + lane]);
            float2 v7 = __half22float2(zl[(size_t)s7 * 64 + lane]);
            ax0 += v0.x + v1.x + v2.x + v3.x;
            ay0 += v0.y + v1.y + v2.y + v3.y;
            ax1 += v4.x + v5.x + v6.x + v7.x;
            ay1 += v4.y + v5.y + v6.y + v7.y;
        }
        for (; j < m; ++j) {
            int s = __builtin_amdgcn_readlane(sv, j);
            float2 v = __half22float2(zl[(size_t)s * 64 + lane]);
            ax0 += v.x;
            ay0 += v.y;
        }
    }
    float ax = ax0 + ax1, ay = ay0 + ay1;

    float inv = frcp((float)(dg + 1));
    float rx = fmaxf(ax * inv, 0.0f);
    float ry = fmaxf(ay * inv, 0.0f);

    // exp0(relu(mean))
    float ss = rx * rx + ry * ry;
    #pragma unroll
    for (int o = 1; o < 64; o <<= 1) ss += __shfl_xor(ss, o);
    float av = fsqrt(fmaxf(ss, EPSF * EPSF));
    float t1 = __expf(av);
    float t1i = frcp(t1);
    float shf = 0.5f * (t1 - t1i) * frcp(av);
    float act0 = 0.5f * (t1 + t1i);
    float asx = shf * rx, asy = shf * ry;

    // load x row
    const float* xr = xin + (size_t)node * DP;
    float x0 = xr[0];
    float xsx = xr[1 + 2 * lane];
    float xsy = xr[2 + 2 * lane];

    // alpha = max(-<x,act>_mink, 1+eps)
    float dot = asx * xsx + asy * xsy;
    #pragma unroll
    for (int o = 1; o < 64; o <<= 1) dot += __shfl_xor(dot, o);
    float mink = dot - act0 * x0;
    float alpha = fmaxf(-mink, 1.0f + EPSF);

    // u = act - alpha*x ; ||u||_mink
    float u0 = act0 - alpha * x0;
    float ux = asx - alpha * xsx;
    float uy = asy - alpha * xsy;
    float uss = ux * ux + uy * uy;
    #pragma unroll
    for (int o = 1; o < 64; o <<= 1) uss += __shfl_xor(uss, o);
    float uu = uss - u0 * u0;
    float un = fsqrt(fmaxf(uu, EPSF * EPSF));

    float d = facosh(alpha);
    float a2 = 0.5f * d;  // beta * dist
    float t2 = __expf(a2);
    float t2i = frcp(t2);
    float ch2 = 0.5f * (t2 + t2i);
    float sh2 = 0.5f * (t2 - t2i) * frcp(un);

    float ox = ch2 * xsx + sh2 * ux;
    float oy = ch2 * xsy + sh2 * uy;

    // proj: recompute time component
    float os = ox * ox + oy * oy;
    #pragma unroll
    for (int o = 1; o < 64; o <<= 1) os += __shfl_xor(os, o);
    float p0 = fsqrt(1.0f + os);

    float* orow = out + (size_t)node * DP;
    if (lane == 0) orow[0] = p0;
    orow[1 + 2 * lane] = ox;
    orow[2 + 2 * lane] = oy;
}

extern "C" void kernel_launch(void* const* d_in, const int* in_sizes, int n_in,
                              void* d_out, int out_size, void* d_ws, size_t ws_size,
                              hipStream_t stream) {
    const float* x  = (const float*)d_in[0];
    const int* ei   = (const int*)d_in[1];
    const float* W1 = (const float*)d_in[2];
    const float* b1 = (const float*)d_in[3];
    const float* W2 = (const float*)d_in[4];
    const float* b2 = (const float*)d_in[5];
    float* out = (float*)d_out;

    int n = in_sizes[0] / DP;      // 65536
    int E = in_sizes[1] / 2;       // 1048576
    const int* src = ei;
    const int* dst = ei + E;

    // workspace carve
    char* w = (char*)d_ws;
    __half* z   = (__half*)w;      w += (size_t)n * D * sizeof(__half);
    int* deg    = (int*)w;         w += (size_t)n * sizeof(int);
    int* off    = (int*)w;         w += (size_t)n * sizeof(int);
    int* ssrc   = (int*)w;         w += ((size_t)E + 64) * sizeof(int);  // +64 pad
    unsigned int* ebuf = (unsigned int*)w; w += (size_t)E * sizeof(unsigned int);
    float* WT1  = (float*)w;       w += (size_t)D * D * sizeof(float);
    float* WT2  = (float*)w;       w += (size_t)D * D * sizeof(float);
    int* bcnt   = (int*)w;         w += 256 * sizeof(int);
    int* bbase  = (int*)w;         w += 256 * sizeof(int);
    int* bcur   = (int*)w;         w += 256 * sizeof(int);

    int tb = (E + TILE - 1) / TILE;  // 256

    // CSR build (shared by both layers)
    k_bzero<<<1, 256, 0, stream>>>(bcnt);
    k_bhist<<<tb, 256, 0, stream>>>(dst, E, bcnt);
    k_bscan<<<1, 256, 0, stream>>>(bcnt, bbase, bcur);
    k_bsplit<<<tb, 256, 0, stream>>>(src, dst, E, bcur, ebuf);
    k_csr<<<256, 256, 0, stream>>>(ebuf, bcnt, bbase, deg, off, ssrc);

    k_transpose<<<(D * D + 255) / 256, 256, 0, stream>>>(W1, WT1);
    k_transpose<<<(D * D + 255) / 256, 256, 0, stream>>>(W2, WT2);

    // layer 1
    k_gemm<<<n / 64, 256, 0, stream>>>(x, WT1, b1, z);
    k_agg<<<n / 4, 256, 0, stream>>>(z, x, off, deg, ssrc, out);

    // layer 2 (in-place on out for the node-wise part)
    k_gemm<<<n / 64, 256, 0, stream>>>(out, WT2, b2, z);
    k_agg<<<n / 4, 256, 0, stream>>>(z, out, off, deg, ssrc, out);
}

// Round 9
// 264.727 us; speedup vs baseline: 2.3204x; 1.2211x over previous
//
#include <hip/hip_runtime.h>
#include <hip/hip_bf16.h>
#include <hip/hip_fp16.h>
#include <math.h>

#define NN 65536
#define NE 1048576
#define D 128
#define DP 129
#define EPSF 1e-6f
#define TILE 4096  // edges per block in k_bhist / k_bsplit (16 per thread)

typedef _Float16 half8 __attribute__((ext_vector_type(8)));
typedef float floatx16 __attribute__((ext_vector_type(16)));

__device__ __forceinline__ float frcp(float x) { return __builtin_amdgcn_rcpf(x); }
__device__ __forceinline__ float fsqrt(float x) { return __builtin_amdgcn_sqrtf(x); }
__device__ __forceinline__ float facosh(float x) {
    // x >= 1+eps; log(x + sqrt(x^2-1))
    return __logf(x + fsqrt(fmaxf(x * x - 1.0f, 0.0f)));
}

// ---- CSR build: two-level multisplit (bucket = dst>>8, 256 buckets) ----

__global__ __launch_bounds__(256) void k_bzero(int* __restrict__ bcnt) {
    bcnt[threadIdx.x] = 0;
}

__global__ __launch_bounds__(256) void k_bhist(const int* __restrict__ dst, int E,
                                               int* __restrict__ bcnt) {
    __shared__ int lh[256];
    int t = threadIdx.x;
    lh[t] = 0;
    __syncthreads();
    int base = blockIdx.x * TILE;
    #pragma unroll
    for (int k = 0; k < 16; ++k) {
        int i = base + k * 256 + t;
        if (i < E) atomicAdd(&lh[dst[i] >> 8], 1);
    }
    __syncthreads();
    if (lh[t]) atomicAdd(&bcnt[t], lh[t]);
}

__global__ __launch_bounds__(256) void k_bscan(const int* __restrict__ bcnt,
                                               int* __restrict__ bbase,
                                               int* __restrict__ bcur) {
    __shared__ int sh[256];
    int t = threadIdx.x;
    int v = bcnt[t];
    sh[t] = v;
    __syncthreads();
    for (int o = 1; o < 256; o <<= 1) {
        int u = (t >= o) ? sh[t - o] : 0;
        __syncthreads();
        sh[t] += u;
        __syncthreads();
    }
    int ex = sh[t] - v;
    bbase[t] = ex;
    bcur[t] = ex;
}

// pack (dst&255)<<16 | src  (src < 65536)
__global__ __launch_bounds__(256) void k_bsplit(const int* __restrict__ src,
                                                const int* __restrict__ dst, int E,
                                                int* __restrict__ bcur,
                                                unsigned int* __restrict__ ebuf) {
    __shared__ int lh[256];
    __shared__ int gres[256];
    int t = threadIdx.x;
    lh[t] = 0;
    __syncthreads();
    int base = blockIdx.x * TILE;
    unsigned int pk[16];
    int bk[16], rk[16];
    #pragma unroll
    for (int k = 0; k < 16; ++k) {
        int i = base + k * 256 + t;
        if (i < E) {
            int d = dst[i];
            int b = d >> 8;
            bk[k] = b;
            pk[k] = ((unsigned)(d & 255) << 16) | (unsigned)src[i];
            rk[k] = atomicAdd(&lh[b], 1);
        } else {
            bk[k] = -1; rk[k] = 0; pk[k] = 0;
        }
    }
    __syncthreads();
    gres[t] = lh[t] ? atomicAdd(&bcur[t], lh[t]) : 0;
    __syncthreads();
    #pragma unroll
    for (int k = 0; k < 16; ++k) {
        if (bk[k] >= 0) ebuf[gres[bk[k]] + rk[k]] = pk[k];
    }
}

// one block per bucket: per-node hist/scan -> deg/off, then local scatter of src
__global__ __launch_bounds__(256) void k_csr(const unsigned int* __restrict__ ebuf,
                                             const int* __restrict__ bcnt,
                                             const int* __restrict__ bbase,
                                             int* __restrict__ deg,
                                             int* __restrict__ off,
                                             int* __restrict__ ssrc) {
    __shared__ int lh[256];
    __shared__ int sc[256];
    __shared__ int lcur[256];
    int t = threadIdx.x;
    int b = blockIdx.x;
    int start = bbase[b];
    int cnt = bcnt[b];
    lh[t] = 0;
    __syncthreads();
    for (int i = t; i < cnt; i += 256) {
        unsigned int e = ebuf[start + i];
        atomicAdd(&lh[e >> 16], 1);
    }
    __syncthreads();
    int v = lh[t];
    sc[t] = v;
    __syncthreads();
    for (int o = 1; o < 256; o <<= 1) {
        int u = (t >= o) ? sc[t - o] : 0;
        __syncthreads();
        sc[t] += u;
        __syncthreads();
    }
    int ex = sc[t] - v;
    int node = (b << 8) + t;
    deg[node] = v;
    off[node] = start + ex;
    lcur[t] = ex;
    __syncthreads();
    for (int i = t; i < cnt; i += 256) {
        unsigned int e = ebuf[start + i];
        int d = e >> 16;
        int r = atomicAdd(&lcur[d], 1);
        ssrc[start + r] = (int)(e & 0xFFFFu);
    }
}

// ---- MFMA GEMM: z[r][j] = sum_k log0(x[r])[k] * W[j][k] + b[j], z in f16 ----
// Block: 256 thr / 4 waves, 128 rows x 128 cols. A (log0 rows) and W staged as
// f16 in LDS, per-row XOR swizzle on 16B chunks (slot ^= row&15) so the
// stride-256B ds_read_b128 fragment reads don't all land on one bank.
// Fragment layouts (mfma_f32_32x32x16_f16):
//   A: row = lane&31, k = (lane>>5)*8 + e   (8 contiguous k per lane)
//   B: col = lane&31, k = (lane>>5)*8 + e   -> lane reads W[col][k..k+7]
//   C: col = lane&31, row = (reg&3) + 8*(reg>>2) + 4*(lane>>5)   [m74/m101]
__global__ __launch_bounds__(256) void k_gemm(const float* __restrict__ x,
                                              const float* __restrict__ W,
                                              const float* __restrict__ bias,
                                              _Float16* __restrict__ z) {
    __shared__ _Float16 Ah[128 * 128];
    __shared__ _Float16 Wh[128 * 128];
    int t = threadIdx.x;
    int w = t >> 6;
    int l = t & 63;
    int j = l & 31;
    int hi = l >> 5;
    int r0 = blockIdx.x * 128;

    // phase 0: stage W (f32 -> f16), swizzled
    #pragma unroll
    for (int i = 0; i < 8; ++i) {
        int c = i * 256 + t;  // chunk id in [0,2048)
        int row = c >> 4, slot = c & 15;
        const float4* wp = (const float4*)(W + row * 128 + slot * 8);
        float4 w0 = wp[0], w1 = wp[1];
        half8 hv;
        hv[0] = (_Float16)w0.x; hv[1] = (_Float16)w0.y;
        hv[2] = (_Float16)w0.z; hv[3] = (_Float16)w0.w;
        hv[4] = (_Float16)w1.x; hv[5] = (_Float16)w1.y;
        hv[6] = (_Float16)w1.z; hv[7] = (_Float16)w1.w;
        *(half8*)&Wh[row * 128 + ((slot ^ (row & 15)) << 3)] = hv;
    }

    // phase 1: log0 rows -> f16 LDS (2 rows per wave-iteration, half-wave each)
    for (int it = 0; it < 16; ++it) {
        int rl = w * 32 + it * 2 + hi;
        const float* xr = x + (size_t)(r0 + rl) * DP;
        float x0 = xr[0];
        float a0 = xr[1 + j];
        float a1 = xr[33 + j];
        float a2 = xr[65 + j];
        float a3 = xr[97 + j];
        float ss = a0 * a0 + a1 * a1 + a2 * a2 + a3 * a3;
        ss += __shfl_xor(ss, 1);
        ss += __shfl_xor(ss, 2);
        ss += __shfl_xor(ss, 4);
        ss += __shfl_xor(ss, 8);
        ss += __shfl_xor(ss, 16);
        float xn = fsqrt(fmaxf(ss, EPSF * EPSF));
        float theta = facosh(fmaxf(x0, 1.0f + EPSF));
        float f = theta * frcp(xn);
        int base = rl * 128;
        int swz = (rl & 15) << 3;
        Ah[base + ((j)      ^ swz)] = (_Float16)(f * a0);
        Ah[base + ((j + 32) ^ swz)] = (_Float16)(f * a1);
        Ah[base + ((j + 64) ^ swz)] = (_Float16)(f * a2);
        Ah[base + ((j + 96) ^ swz)] = (_Float16)(f * a3);
    }
    __syncthreads();

    // main: 8 K-steps x 4 col-tiles of mfma 32x32x16
    int rA = w * 32 + j;                 // (rA & 15) == (j & 15)
    int swzj = (j & 15) << 3;
    const _Float16* Abase = &Ah[rA * 128];
    const _Float16* B0 = &Wh[(j)*128];
    const _Float16* B1 = &Wh[(j + 32) * 128];
    const _Float16* B2 = &Wh[(j + 64) * 128];
    const _Float16* B3 = &Wh[(j + 96) * 128];

    float bv0 = bias[j], bv1 = bias[j + 32], bv2 = bias[j + 64], bv3 = bias[j + 96];
    floatx16 acc0, acc1, acc2, acc3;
    #pragma unroll
    for (int q = 0; q < 16; ++q) {
        acc0[q] = bv0; acc1[q] = bv1; acc2[q] = bv2; acc3[q] = bv3;
    }

    #pragma unroll
    for (int ks = 0; ks < 8; ++ks) {
        int kh = (ks * 16 + hi * 8) ^ swzj;
        half8 a  = *(const half8*)(Abase + kh);
        half8 b0 = *(const half8*)(B0 + kh);
        half8 b1 = *(const half8*)(B1 + kh);
        half8 b2 = *(const half8*)(B2 + kh);
        half8 b3 = *(const half8*)(B3 + kh);
        acc0 = __builtin_amdgcn_mfma_f32_32x32x16_f16(a, b0, acc0, 0, 0, 0);
        acc1 = __builtin_amdgcn_mfma_f32_32x32x16_f16(a, b1, acc1, 0, 0, 0);
        acc2 = __builtin_amdgcn_mfma_f32_32x32x16_f16(a, b2, acc2, 0, 0, 0);
        acc3 = __builtin_amdgcn_mfma_f32_32x32x16_f16(a, b3, acc3, 0, 0, 0);
    }

    // epilogue: C layout col = j (+tile), row = (q&3) + 8*(q>>2) + 4*hi
    #pragma unroll
    for (int q = 0; q < 16; ++q) {
        int row = r0 + w * 32 + (q & 3) + 8 * (q >> 2) + 4 * hi;
        size_t rb = (size_t)row * 128 + j;
        z[rb]      = (_Float16)acc0[q];
        z[rb + 32] = (_Float16)acc1[q];
        z[rb + 64] = (_Float16)acc2[q];
        z[rb + 96] = (_Float16)acc3[q];
    }
}

// One wave per node. Wave-uniform values (node, off, deg, edge ids) pinned to
// SGPRs: gather is SGPR row base + lane offset. Epilogue: shared-exp sinh/cosh.
__global__ __launch_bounds__(256) void k_agg(const __half* __restrict__ z,
                                             const float* xin,
                                             const int* __restrict__ off,
                                             const int* __restrict__ deg,
                                             const int* __restrict__ ssrc,
                                             float* out) {
    int wave = threadIdx.x >> 6, lane = threadIdx.x & 63;
    int node = __builtin_amdgcn_readfirstlane(blockIdx.x * 4 + wave);

    const __half2* zl = (const __half2*)z;

    // self loop
    float2 a = __half22float2(zl[(size_t)node * 64 + lane]);
    float ax0 = a.x, ay0 = a.y, ax1 = 0.f, ay1 = 0.f;

    int start = __builtin_amdgcn_readfirstlane(off[node]);
    int dg = __builtin_amdgcn_readfirstlane(deg[node]);

    for (int c = 0; c < dg; c += 64) {
        int rem = dg - c;
        int m = rem < 64 ? rem : 64;
        int sv = ssrc[start + c + lane];  // ssrc padded by 64 -> no guard
        int j = 0;
        for (; j + 7 < m; j += 8) {
            int s0 = __builtin_amdgcn_readlane(sv, j + 0);
            int s1 = __builtin_amdgcn_readlane(sv, j + 1);
            int s2 = __builtin_amdgcn_readlane(sv, j + 2);
            int s3 = __builtin_amdgcn_readlane(sv, j + 3);
            int s4 = __builtin_amdgcn_readlane(sv, j + 4);
            int s5 = __builtin_amdgcn_readlane(sv, j + 5);
            int s6 = __builtin_amdgcn_readlane(sv, j + 6);
            int s7 = __builtin_amdgcn_readlane(sv, j + 7);
            float2 v0 = __half22float2(zl[(size_t)s0 * 64 + lane]);
            float2 v1 = __half22float2(zl[(size_t)s1 * 64 + lane]);
            float2 v2 = __half22float2(zl[(size_t)s2 * 64 + lane]);
            float2 v3 = __half22float2(zl[(size_t)s3 * 64 + lane]);
            float2 v4 = __half22float2(zl[(size_t)s4 * 64 + lane]);
            float2 v5 = __half22float2(zl[(size_t)s5 * 64 + lane]);
            float2 v6 = __half22float2(zl[(size_t)s6 * 64 + lane]);
            float2 v7 = __half22float2(zl[(size_t)s7 * 64 + lane]);
            ax0 += v0.x + v1.x + v2.x + v3.x;
            ay0 += v0.y + v1.y + v2.y + v3.y;
            ax1 += v4.x + v5.x + v6.x + v7.x;
            ay1 += v4.y + v5.y + v6.y + v7.y;
        }
        for (; j < m; ++j) {
            int s = __builtin_amdgcn_readlane(sv, j);
            float2 v = __half22float2(zl[(size_t)s * 64 + lane]);
            ax0 += v.x;
            ay0 += v.y;
        }
    }
    float ax = ax0 + ax1, ay = ay0 + ay1;

    float inv = frcp((float)(dg + 1));
    float rx = fmaxf(ax * inv, 0.0f);
    float ry = fmaxf(ay * inv, 0.0f);

    // exp0(relu(mean))
    float ss = rx * rx + ry * ry;
    #pragma unroll
    for (int o = 1; o < 64; o <<= 1) ss += __shfl_xor(ss, o);
    float av = fsqrt(fmaxf(ss, EPSF * EPSF));
    float t1 = __expf(av);
    float t1i = frcp(t1);
    float shf = 0.5f * (t1 - t1i) * frcp(av);
    float act0 = 0.5f * (t1 + t1i);
    float asx = shf * rx, asy = shf * ry;

    // load x row
    const float* xr = xin + (size_t)node * DP;
    float x0 = xr[0];
    float xsx = xr[1 + 2 * lane];
    float xsy = xr[2 + 2 * lane];

    // alpha = max(-<x,act>_mink, 1+eps)
    float dot = asx * xsx + asy * xsy;
    #pragma unroll
    for (int o = 1; o < 64; o <<= 1) dot += __shfl_xor(dot, o);
    float mink = dot - act0 * x0;
    float alpha = fmaxf(-mink, 1.0f + EPSF);

    // u = act - alpha*x ; ||u||_mink
    float u0 = act0 - alpha * x0;
    float ux = asx - alpha * xsx;
    float uy = asy - alpha * xsy;
    float uss = ux * ux + uy * uy;
    #pragma unroll
    for (int o = 1; o < 64; o <<= 1) uss += __shfl_xor(uss, o);
    float uu = uss - u0 * u0;
    float un = fsqrt(fmaxf(uu, EPSF * EPSF));

    float d = facosh(alpha);
    float a2 = 0.5f * d;  // beta * dist
    float t2 = __expf(a2);
    float t2i = frcp(t2);
    float ch2 = 0.5f * (t2 + t2i);
    float sh2 = 0.5f * (t2 - t2i) * frcp(un);

    float ox = ch2 * xsx + sh2 * ux;
    float oy = ch2 * xsy + sh2 * uy;

    // proj: recompute time component
    float os = ox * ox + oy * oy;
    #pragma unroll
    for (int o = 1; o < 64; o <<= 1) os += __shfl_xor(os, o);
    float p0 = fsqrt(1.0f + os);

    float* orow = out + (size_t)node * DP;
    if (lane == 0) orow[0] = p0;
    orow[1 + 2 * lane] = ox;
    orow[2 + 2 * lane] = oy;
}

extern "C" void kernel_launch(void* const* d_in, const int* in_sizes, int n_in,
                              void* d_out, int out_size, void* d_ws, size_t ws_size,
                              hipStream_t stream) {
    const float* x  = (const float*)d_in[0];
    const int* ei   = (const int*)d_in[1];
    const float* W1 = (const float*)d_in[2];
    const float* b1 = (const float*)d_in[3];
    const float* W2 = (const float*)d_in[4];
    const float* b2 = (const float*)d_in[5];
    float* out = (float*)d_out;

    int n = in_sizes[0] / DP;      // 65536
    int E = in_sizes[1] / 2;       // 1048576
    const int* src = ei;
    const int* dst = ei + E;

    // workspace carve
    char* w = (char*)d_ws;
    __half* z   = (__half*)w;      w += (size_t)n * D * sizeof(__half);
    int* deg    = (int*)w;         w += (size_t)n * sizeof(int);
    int* off    = (int*)w;         w += (size_t)n * sizeof(int);
    int* ssrc   = (int*)w;         w += ((size_t)E + 64) * sizeof(int);  // +64 pad
    unsigned int* ebuf = (unsigned int*)w; w += (size_t)E * sizeof(unsigned int);
    int* bcnt   = (int*)w;         w += 256 * sizeof(int);
    int* bbase  = (int*)w;         w += 256 * sizeof(int);
    int* bcur   = (int*)w;         w += 256 * sizeof(int);

    int tb = (E + TILE - 1) / TILE;  // 256

    // CSR build (shared by both layers)
    k_bzero<<<1, 256, 0, stream>>>(bcnt);
    k_bhist<<<tb, 256, 0, stream>>>(dst, E, bcnt);
    k_bscan<<<1, 256, 0, stream>>>(bcnt, bbase, bcur);
    k_bsplit<<<tb, 256, 0, stream>>>(src, dst, E, bcur, ebuf);
    k_csr<<<256, 256, 0, stream>>>(ebuf, bcnt, bbase, deg, off, ssrc);

    // layer 1
    k_gemm<<<n / 128, 256, 0, stream>>>(x, W1, b1, (_Float16*)z);
    k_agg<<<n / 4, 256, 0, stream>>>(z, x, off, deg, ssrc, out);

    // layer 2 (in-place on out for the node-wise part)
    k_gemm<<<n / 128, 256, 0, stream>>>(out, W2, b2, (_Float16*)z);
    k_agg<<<n / 4, 256, 0, stream>>>(z, out, off, deg, ssrc, out);
}

// Round 10
// 246.320 us; speedup vs baseline: 2.4938x; 1.0747x over previous
//
#include <hip/hip_runtime.h>
#include <hip/hip_bf16.h>
#include <hip/hip_fp16.h>
#include <math.h>

#define NN 65536
#define NE 1048576
#define D 128
#define DP 129
#define EPSF 1e-6f
#define TILE 4096  // edges per block in k_bhist / k_bsplit (16 per thread)

typedef _Float16 half8 __attribute__((ext_vector_type(8)));
typedef float floatx16 __attribute__((ext_vector_type(16)));
typedef float floatx2 __attribute__((ext_vector_type(2)));

__device__ __forceinline__ float frcp(float x) { return __builtin_amdgcn_rcpf(x); }
__device__ __forceinline__ float fsqrt(float x) { return __builtin_amdgcn_sqrtf(x); }
__device__ __forceinline__ float facosh(float x) {
    // x >= 1+eps; log(x + sqrt(x^2-1))
    return __logf(x + fsqrt(fmaxf(x * x - 1.0f, 0.0f)));
}

// ---- CSR build: two-level multisplit (bucket = dst>>8, 256 buckets) ----

__global__ __launch_bounds__(256) void k_bzero(int* __restrict__ bcnt) {
    bcnt[threadIdx.x] = 0;
}

__global__ __launch_bounds__(256) void k_bhist(const int* __restrict__ dst, int E,
                                               int* __restrict__ bcnt) {
    __shared__ int lh[256];
    int t = threadIdx.x;
    lh[t] = 0;
    __syncthreads();
    int base = blockIdx.x * TILE;
    #pragma unroll
    for (int k = 0; k < 16; ++k) {
        int i = base + k * 256 + t;
        if (i < E) atomicAdd(&lh[dst[i] >> 8], 1);
    }
    __syncthreads();
    if (lh[t]) atomicAdd(&bcnt[t], lh[t]);
}

__global__ __launch_bounds__(256) void k_bscan(const int* __restrict__ bcnt,
                                               int* __restrict__ bbase,
                                               int* __restrict__ bcur) {
    __shared__ int sh[256];
    int t = threadIdx.x;
    int v = bcnt[t];
    sh[t] = v;
    __syncthreads();
    for (int o = 1; o < 256; o <<= 1) {
        int u = (t >= o) ? sh[t - o] : 0;
        __syncthreads();
        sh[t] += u;
        __syncthreads();
    }
    int ex = sh[t] - v;
    bbase[t] = ex;
    bcur[t] = ex;
}

// pack (dst&255)<<16 | src  (src < 65536)
__global__ __launch_bounds__(256) void k_bsplit(const int* __restrict__ src,
                                                const int* __restrict__ dst, int E,
                                                int* __restrict__ bcur,
                                                unsigned int* __restrict__ ebuf) {
    __shared__ int lh[256];
    __shared__ int gres[256];
    int t = threadIdx.x;
    lh[t] = 0;
    __syncthreads();
    int base = blockIdx.x * TILE;
    unsigned int pk[16];
    int bk[16], rk[16];
    #pragma unroll
    for (int k = 0; k < 16; ++k) {
        int i = base + k * 256 + t;
        if (i < E) {
            int d = dst[i];
            int b = d >> 8;
            bk[k] = b;
            pk[k] = ((unsigned)(d & 255) << 16) | (unsigned)src[i];
            rk[k] = atomicAdd(&lh[b], 1);
        } else {
            bk[k] = -1; rk[k] = 0; pk[k] = 0;
        }
    }
    __syncthreads();
    gres[t] = lh[t] ? atomicAdd(&bcur[t], lh[t]) : 0;
    __syncthreads();
    #pragma unroll
    for (int k = 0; k < 16; ++k) {
        if (bk[k] >= 0) ebuf[gres[bk[k]] + rk[k]] = pk[k];
    }
}

// one block per bucket: per-node hist/scan -> deg/off, then local scatter of src
__global__ __launch_bounds__(256) void k_csr(const unsigned int* __restrict__ ebuf,
                                             const int* __restrict__ bcnt,
                                             const int* __restrict__ bbase,
                                             int* __restrict__ deg,
                                             int* __restrict__ off,
                                             int* __restrict__ ssrc) {
    __shared__ int lh[256];
    __shared__ int sc[256];
    __shared__ int lcur[256];
    int t = threadIdx.x;
    int b = blockIdx.x;
    int start = bbase[b];
    int cnt = bcnt[b];
    lh[t] = 0;
    __syncthreads();
    for (int i = t; i < cnt; i += 256) {
        unsigned int e = ebuf[start + i];
        atomicAdd(&lh[e >> 16], 1);
    }
    __syncthreads();
    int v = lh[t];
    sc[t] = v;
    __syncthreads();
    for (int o = 1; o < 256; o <<= 1) {
        int u = (t >= o) ? sc[t - o] : 0;
        __syncthreads();
        sc[t] += u;
        __syncthreads();
    }
    int ex = sc[t] - v;
    int node = (b << 8) + t;
    deg[node] = v;
    off[node] = start + ex;
    lcur[t] = ex;
    __syncthreads();
    for (int i = t; i < cnt; i += 256) {
        unsigned int e = ebuf[start + i];
        int d = e >> 16;
        int r = atomicAdd(&lcur[d], 1);
        ssrc[start + r] = (int)(e & 0xFFFFu);
    }
}

// ---- MFMA GEMM: z[r][j] = sum_k log0(x[r])[k] * W[j][k] + b[j] ----
// z stored as fp8 e4m3, tile-permuted: dword d of a 128-B row holds cols
// [d, d+32, d+64, d+96] -> the C-fragment (cols j, j+32, j+64, j+96) packs
// into ONE dword store per row via 2x v_cvt_pk_fp8_f32.
// Fragment layouts (mfma_f32_32x32x16_f16):
//   A: row = lane&31, k = (lane>>5)*8 + e ; B: col = lane&31, same k
//   C: col = lane&31, row = (reg&3) + 8*(reg>>2) + 4*(lane>>5)   [m74/m101]
__global__ __launch_bounds__(256) void k_gemm(const float* __restrict__ x,
                                              const float* __restrict__ W,
                                              const float* __restrict__ bias,
                                              unsigned int* __restrict__ zw) {
    __shared__ _Float16 Ah[128 * 128];
    __shared__ _Float16 Wh[128 * 128];
    int t = threadIdx.x;
    int w = t >> 6;
    int l = t & 63;
    int j = l & 31;
    int hi = l >> 5;
    int r0 = blockIdx.x * 128;

    // phase 0: stage W (f32 -> f16), swizzled
    #pragma unroll
    for (int i = 0; i < 8; ++i) {
        int c = i * 256 + t;  // chunk id in [0,2048)
        int row = c >> 4, slot = c & 15;
        const float4* wp = (const float4*)(W + row * 128 + slot * 8);
        float4 w0 = wp[0], w1 = wp[1];
        half8 hv;
        hv[0] = (_Float16)w0.x; hv[1] = (_Float16)w0.y;
        hv[2] = (_Float16)w0.z; hv[3] = (_Float16)w0.w;
        hv[4] = (_Float16)w1.x; hv[5] = (_Float16)w1.y;
        hv[6] = (_Float16)w1.z; hv[7] = (_Float16)w1.w;
        *(half8*)&Wh[row * 128 + ((slot ^ (row & 15)) << 3)] = hv;
    }

    // phase 1: log0 rows -> f16 LDS (2 rows per wave-iteration, half-wave each)
    for (int it = 0; it < 16; ++it) {
        int rl = w * 32 + it * 2 + hi;
        const float* xr = x + (size_t)(r0 + rl) * DP;
        float x0 = xr[0];
        float a0 = xr[1 + j];
        float a1 = xr[33 + j];
        float a2 = xr[65 + j];
        float a3 = xr[97 + j];
        float ss = a0 * a0 + a1 * a1 + a2 * a2 + a3 * a3;
        ss += __shfl_xor(ss, 1);
        ss += __shfl_xor(ss, 2);
        ss += __shfl_xor(ss, 4);
        ss += __shfl_xor(ss, 8);
        ss += __shfl_xor(ss, 16);
        float xn = fsqrt(fmaxf(ss, EPSF * EPSF));
        float theta = facosh(fmaxf(x0, 1.0f + EPSF));
        float f = theta * frcp(xn);
        int base = rl * 128;
        int swz = (rl & 15) << 3;
        Ah[base + ((j)      ^ swz)] = (_Float16)(f * a0);
        Ah[base + ((j + 32) ^ swz)] = (_Float16)(f * a1);
        Ah[base + ((j + 64) ^ swz)] = (_Float16)(f * a2);
        Ah[base + ((j + 96) ^ swz)] = (_Float16)(f * a3);
    }
    __syncthreads();

    // main: 8 K-steps x 4 col-tiles of mfma 32x32x16
    int rA = w * 32 + j;                 // (rA & 15) == (j & 15)
    int swzj = (j & 15) << 3;
    const _Float16* Abase = &Ah[rA * 128];
    const _Float16* B0 = &Wh[(j)*128];
    const _Float16* B1 = &Wh[(j + 32) * 128];
    const _Float16* B2 = &Wh[(j + 64) * 128];
    const _Float16* B3 = &Wh[(j + 96) * 128];

    float bv0 = bias[j], bv1 = bias[j + 32], bv2 = bias[j + 64], bv3 = bias[j + 96];
    floatx16 acc0, acc1, acc2, acc3;
    #pragma unroll
    for (int q = 0; q < 16; ++q) {
        acc0[q] = bv0; acc1[q] = bv1; acc2[q] = bv2; acc3[q] = bv3;
    }

    #pragma unroll
    for (int ks = 0; ks < 8; ++ks) {
        int kh = (ks * 16 + hi * 8) ^ swzj;
        half8 a  = *(const half8*)(Abase + kh);
        half8 b0 = *(const half8*)(B0 + kh);
        half8 b1 = *(const half8*)(B1 + kh);
        half8 b2 = *(const half8*)(B2 + kh);
        half8 b3 = *(const half8*)(B3 + kh);
        acc0 = __builtin_amdgcn_mfma_f32_32x32x16_f16(a, b0, acc0, 0, 0, 0);
        acc1 = __builtin_amdgcn_mfma_f32_32x32x16_f16(a, b1, acc1, 0, 0, 0);
        acc2 = __builtin_amdgcn_mfma_f32_32x32x16_f16(a, b2, acc2, 0, 0, 0);
        acc3 = __builtin_amdgcn_mfma_f32_32x32x16_f16(a, b3, acc3, 0, 0, 0);
    }

    // epilogue: pack 4 cols (j, j+32, j+64, j+96) -> one fp8 dword at word j
    #pragma unroll
    for (int q = 0; q < 16; ++q) {
        int row = r0 + w * 32 + (q & 3) + 8 * (q >> 2) + 4 * hi;
        unsigned int u = 0;
        u = (unsigned int)__builtin_amdgcn_cvt_pk_fp8_f32(acc0[q], acc1[q], (int)u, false);
        u = (unsigned int)__builtin_amdgcn_cvt_pk_fp8_f32(acc2[q], acc3[q], (int)u, true);
        zw[(size_t)row * 32 + j] = u;
    }
}

// One wave per node. Wave-uniform values (node, off, deg, edge ids) pinned to
// SGPRs: gather is SGPR row base + lane offset (ushort = 2 fp8 dims/lane).
// Lane l holds cols c0 = (l>>1) + 64*(l&1), c1 = c0 + 32 (z tile-permuted).
__global__ __launch_bounds__(256) void k_agg(const unsigned short* __restrict__ zs,
                                             const float* xin,
                                             const int* __restrict__ off,
                                             const int* __restrict__ deg,
                                             const int* __restrict__ ssrc,
                                             float* out) {
    int wave = threadIdx.x >> 6, lane = threadIdx.x & 63;
    int node = __builtin_amdgcn_readfirstlane(blockIdx.x * 4 + wave);
    int c0 = (lane >> 1) + ((lane & 1) << 6);

    // self loop
    floatx2 a = __builtin_amdgcn_cvt_pk_f32_fp8((int)zs[(size_t)node * 64 + lane], false);
    float ax0 = a.x, ay0 = a.y, ax1 = 0.f, ay1 = 0.f;

    int start = __builtin_amdgcn_readfirstlane(off[node]);
    int dg = __builtin_amdgcn_readfirstlane(deg[node]);

    for (int c = 0; c < dg; c += 64) {
        int rem = dg - c;
        int m = rem < 64 ? rem : 64;
        int sv = ssrc[start + c + lane];  // ssrc padded by 64 -> no guard
        int j = 0;
        for (; j + 7 < m; j += 8) {
            int s0 = __builtin_amdgcn_readlane(sv, j + 0);
            int s1 = __builtin_amdgcn_readlane(sv, j + 1);
            int s2 = __builtin_amdgcn_readlane(sv, j + 2);
            int s3 = __builtin_amdgcn_readlane(sv, j + 3);
            int s4 = __builtin_amdgcn_readlane(sv, j + 4);
            int s5 = __builtin_amdgcn_readlane(sv, j + 5);
            int s6 = __builtin_amdgcn_readlane(sv, j + 6);
            int s7 = __builtin_amdgcn_readlane(sv, j + 7);
            floatx2 v0 = __builtin_amdgcn_cvt_pk_f32_fp8((int)zs[(size_t)s0 * 64 + lane], false);
            floatx2 v1 = __builtin_amdgcn_cvt_pk_f32_fp8((int)zs[(size_t)s1 * 64 + lane], false);
            floatx2 v2 = __builtin_amdgcn_cvt_pk_f32_fp8((int)zs[(size_t)s2 * 64 + lane], false);
            floatx2 v3 = __builtin_amdgcn_cvt_pk_f32_fp8((int)zs[(size_t)s3 * 64 + lane], false);
            floatx2 v4 = __builtin_amdgcn_cvt_pk_f32_fp8((int)zs[(size_t)s4 * 64 + lane], false);
            floatx2 v5 = __builtin_amdgcn_cvt_pk_f32_fp8((int)zs[(size_t)s5 * 64 + lane], false);
            floatx2 v6 = __builtin_amdgcn_cvt_pk_f32_fp8((int)zs[(size_t)s6 * 64 + lane], false);
            floatx2 v7 = __builtin_amdgcn_cvt_pk_f32_fp8((int)zs[(size_t)s7 * 64 + lane], false);
            ax0 += v0.x + v1.x + v2.x + v3.x;
            ay0 += v0.y + v1.y + v2.y + v3.y;
            ax1 += v4.x + v5.x + v6.x + v7.x;
            ay1 += v4.y + v5.y + v6.y + v7.y;
        }
        for (; j < m; ++j) {
            int s = __builtin_amdgcn_readlane(sv, j);
            floatx2 v = __builtin_amdgcn_cvt_pk_f32_fp8((int)zs[(size_t)s * 64 + lane], false);
            ax0 += v.x;
            ay0 += v.y;
        }
    }
    float ax = ax0 + ax1, ay = ay0 + ay1;

    float inv = frcp((float)(dg + 1));
    float rx = fmaxf(ax * inv, 0.0f);
    float ry = fmaxf(ay * inv, 0.0f);

    // exp0(relu(mean))
    float ss = rx * rx + ry * ry;
    #pragma unroll
    for (int o = 1; o < 64; o <<= 1) ss += __shfl_xor(ss, o);
    float av = fsqrt(fmaxf(ss, EPSF * EPSF));
    float t1 = __expf(av);
    float t1i = frcp(t1);
    float shf = 0.5f * (t1 - t1i) * frcp(av);
    float act0 = 0.5f * (t1 + t1i);
    float asx = shf * rx, asy = shf * ry;

    // load x row (dims c0, c0+32)
    const float* xr = xin + (size_t)node * DP;
    float x0 = xr[0];
    float xsx = xr[1 + c0];
    float xsy = xr[33 + c0];

    // alpha = max(-<x,act>_mink, 1+eps)
    float dot = asx * xsx + asy * xsy;
    #pragma unroll
    for (int o = 1; o < 64; o <<= 1) dot += __shfl_xor(dot, o);
    float mink = dot - act0 * x0;
    float alpha = fmaxf(-mink, 1.0f + EPSF);

    // u = act - alpha*x ; ||u||_mink
    float u0 = act0 - alpha * x0;
    float ux = asx - alpha * xsx;
    float uy = asy - alpha * xsy;
    float uss = ux * ux + uy * uy;
    #pragma unroll
    for (int o = 1; o < 64; o <<= 1) uss += __shfl_xor(uss, o);
    float uu = uss - u0 * u0;
    float un = fsqrt(fmaxf(uu, EPSF * EPSF));

    float d = facosh(alpha);
    float a2 = 0.5f * d;  // beta * dist
    float t2 = __expf(a2);
    float t2i = frcp(t2);
    float ch2 = 0.5f * (t2 + t2i);
    float sh2 = 0.5f * (t2 - t2i) * frcp(un);

    float ox = ch2 * xsx + sh2 * ux;
    float oy = ch2 * xsy + sh2 * uy;

    // proj: recompute time component
    float os = ox * ox + oy * oy;
    #pragma unroll
    for (int o = 1; o < 64; o <<= 1) os += __shfl_xor(os, o);
    float p0 = fsqrt(1.0f + os);

    float* orow = out + (size_t)node * DP;
    if (lane == 0) orow[0] = p0;
    orow[1 + c0] = ox;
    orow[33 + c0] = oy;
}

extern "C" void kernel_launch(void* const* d_in, const int* in_sizes, int n_in,
                              void* d_out, int out_size, void* d_ws, size_t ws_size,
                              hipStream_t stream) {
    const float* x  = (const float*)d_in[0];
    const int* ei   = (const int*)d_in[1];
    const float* W1 = (const float*)d_in[2];
    const float* b1 = (const float*)d_in[3];
    const float* W2 = (const float*)d_in[4];
    const float* b2 = (const float*)d_in[5];
    float* out = (float*)d_out;

    int n = in_sizes[0] / DP;      // 65536
    int E = in_sizes[1] / 2;       // 1048576
    const int* src = ei;
    const int* dst = ei + E;

    // workspace carve
    char* w = (char*)d_ws;
    unsigned char* z8 = (unsigned char*)w; w += (size_t)n * D;  // fp8 z, 8 MB
    int* deg    = (int*)w;         w += (size_t)n * sizeof(int);
    int* off    = (int*)w;         w += (size_t)n * sizeof(int);
    int* ssrc   = (int*)w;         w += ((size_t)E + 64) * sizeof(int);  // +64 pad
    unsigned int* ebuf = (unsigned int*)w; w += (size_t)E * sizeof(unsigned int);
    int* bcnt   = (int*)w;         w += 256 * sizeof(int);
    int* bbase  = (int*)w;         w += 256 * sizeof(int);
    int* bcur   = (int*)w;         w += 256 * sizeof(int);

    int tb = (E + TILE - 1) / TILE;  // 256

    // CSR build (shared by both layers)
    k_bzero<<<1, 256, 0, stream>>>(bcnt);
    k_bhist<<<tb, 256, 0, stream>>>(dst, E, bcnt);
    k_bscan<<<1, 256, 0, stream>>>(bcnt, bbase, bcur);
    k_bsplit<<<tb, 256, 0, stream>>>(src, dst, E, bcur, ebuf);
    k_csr<<<256, 256, 0, stream>>>(ebuf, bcnt, bbase, deg, off, ssrc);

    // layer 1
    k_gemm<<<n / 128, 256, 0, stream>>>(x, W1, b1, (unsigned int*)z8);
    k_agg<<<n / 4, 256, 0, stream>>>((const unsigned short*)z8, x, off, deg, ssrc, out);

    // layer 2 (in-place on out for the node-wise part)
    k_gemm<<<n / 128, 256, 0, stream>>>(out, W2, b2, (unsigned int*)z8);
    k_agg<<<n / 4, 256, 0, stream>>>((const unsigned short*)z8, out, off, deg, ssrc, out);
}

// Round 11
// 243.856 us; speedup vs baseline: 2.5190x; 1.0101x over previous
//
#include <hip/hip_runtime.h>
#include <hip/hip_bf16.h>
#include <hip/hip_fp16.h>
#include <math.h>

#define NN 65536
#define NE 1048576
#define D 128
#define DP 129
#define EPSF 1e-6f
#define TILE 4096  // edges per block in k_bhist / k_bsplit (16 per thread)

typedef _Float16 half8 __attribute__((ext_vector_type(8)));
typedef float floatx16 __attribute__((ext_vector_type(16)));
typedef float floatx2 __attribute__((ext_vector_type(2)));

__device__ __forceinline__ float frcp(float x) { return __builtin_amdgcn_rcpf(x); }
__device__ __forceinline__ float fsqrt(float x) { return __builtin_amdgcn_sqrtf(x); }
__device__ __forceinline__ float facosh(float x) {
    // x >= 1+eps; log(x + sqrt(x^2-1))
    return __logf(x + fsqrt(fmaxf(x * x - 1.0f, 0.0f)));
}

// ---- CSR build: two-level multisplit (bucket = dst>>8, 256 buckets) ----

__global__ __launch_bounds__(256) void k_bzero(int* __restrict__ bcnt) {
    bcnt[threadIdx.x] = 0;
}

__global__ __launch_bounds__(256) void k_bhist(const int* __restrict__ dst, int E,
                                               int* __restrict__ bcnt) {
    __shared__ int lh[256];
    int t = threadIdx.x;
    lh[t] = 0;
    __syncthreads();
    int base = blockIdx.x * TILE;
    #pragma unroll
    for (int k = 0; k < 16; ++k) {
        int i = base + k * 256 + t;
        if (i < E) atomicAdd(&lh[dst[i] >> 8], 1);
    }
    __syncthreads();
    if (lh[t]) atomicAdd(&bcnt[t], lh[t]);
}

__global__ __launch_bounds__(256) void k_bscan(const int* __restrict__ bcnt,
                                               int* __restrict__ bbase,
                                               int* __restrict__ bcur) {
    __shared__ int sh[256];
    int t = threadIdx.x;
    int v = bcnt[t];
    sh[t] = v;
    __syncthreads();
    for (int o = 1; o < 256; o <<= 1) {
        int u = (t >= o) ? sh[t - o] : 0;
        __syncthreads();
        sh[t] += u;
        __syncthreads();
    }
    int ex = sh[t] - v;
    bbase[t] = ex;
    bcur[t] = ex;
}

// pack (dst&255)<<16 | src  (src < 65536)
__global__ __launch_bounds__(256) void k_bsplit(const int* __restrict__ src,
                                                const int* __restrict__ dst, int E,
                                                int* __restrict__ bcur,
                                                unsigned int* __restrict__ ebuf) {
    __shared__ int lh[256];
    __shared__ int gres[256];
    int t = threadIdx.x;
    lh[t] = 0;
    __syncthreads();
    int base = blockIdx.x * TILE;
    unsigned int pk[16];
    int bk[16], rk[16];
    #pragma unroll
    for (int k = 0; k < 16; ++k) {
        int i = base + k * 256 + t;
        if (i < E) {
            int d = dst[i];
            int b = d >> 8;
            bk[k] = b;
            pk[k] = ((unsigned)(d & 255) << 16) | (unsigned)src[i];
            rk[k] = atomicAdd(&lh[b], 1);
        } else {
            bk[k] = -1; rk[k] = 0; pk[k] = 0;
        }
    }
    __syncthreads();
    gres[t] = lh[t] ? atomicAdd(&bcur[t], lh[t]) : 0;
    __syncthreads();
    #pragma unroll
    for (int k = 0; k < 16; ++k) {
        if (bk[k] >= 0) ebuf[gres[bk[k]] + rk[k]] = pk[k];
    }
}

// one block per bucket: per-node hist/scan -> deg/off, then local scatter of src
__global__ __launch_bounds__(256) void k_csr(const unsigned int* __restrict__ ebuf,
                                             const int* __restrict__ bcnt,
                                             const int* __restrict__ bbase,
                                             int* __restrict__ deg,
                                             int* __restrict__ off,
                                             int* __restrict__ ssrc) {
    __shared__ int lh[256];
    __shared__ int sc[256];
    __shared__ int lcur[256];
    int t = threadIdx.x;
    int b = blockIdx.x;
    int start = bbase[b];
    int cnt = bcnt[b];
    lh[t] = 0;
    __syncthreads();
    for (int i = t; i < cnt; i += 256) {
        unsigned int e = ebuf[start + i];
        atomicAdd(&lh[e >> 16], 1);
    }
    __syncthreads();
    int v = lh[t];
    sc[t] = v;
    __syncthreads();
    for (int o = 1; o < 256; o <<= 1) {
        int u = (t >= o) ? sc[t - o] : 0;
        __syncthreads();
        sc[t] += u;
        __syncthreads();
    }
    int ex = sc[t] - v;
    int node = (b << 8) + t;
    deg[node] = v;
    off[node] = start + ex;
    lcur[t] = ex;
    __syncthreads();
    for (int i = t; i < cnt; i += 256) {
        unsigned int e = ebuf[start + i];
        int d = e >> 16;
        int r = atomicAdd(&lcur[d], 1);
        ssrc[start + r] = (int)(e & 0xFFFFu);
    }
}

// ---- MFMA GEMM: z[r][j] = sum_k A[r][k] * W[j][k] + b[j] ----
// A = log0(x) computed in-kernel (layer 1, FROM_F16=false) or pre-computed
// f16 y rows (layer 2, FROM_F16=true, written by k_agg<WRITE_Y=true>).
// z stored as fp8 e4m3, tile-permuted: dword d of a 128-B row holds cols
// [d, d+32, d+64, d+96] -> C-fragment packs into ONE dword store per row.
// Fragment layouts (mfma_f32_32x32x16_f16):
//   A: row = lane&31, k = (lane>>5)*8 + e ; B: col = lane&31, same k
//   C: col = lane&31, row = (reg&3) + 8*(reg>>2) + 4*(lane>>5)   [m74/m101]
template <bool FROM_F16>
__global__ __launch_bounds__(256) void k_gemm(const float* __restrict__ x,
                                              const _Float16* __restrict__ y,
                                              const float* __restrict__ W,
                                              const float* __restrict__ bias,
                                              unsigned int* __restrict__ zw) {
    __shared__ _Float16 Ah[128 * 128];
    __shared__ _Float16 Wh[128 * 128];
    int t = threadIdx.x;
    int w = t >> 6;
    int l = t & 63;
    int j = l & 31;
    int hi = l >> 5;
    int r0 = blockIdx.x * 128;

    // phase 0: stage W (f32 -> f16), swizzled
    #pragma unroll
    for (int i = 0; i < 8; ++i) {
        int c = i * 256 + t;  // chunk id in [0,2048)
        int row = c >> 4, slot = c & 15;
        const float4* wp = (const float4*)(W + row * 128 + slot * 8);
        float4 w0 = wp[0], w1 = wp[1];
        half8 hv;
        hv[0] = (_Float16)w0.x; hv[1] = (_Float16)w0.y;
        hv[2] = (_Float16)w0.z; hv[3] = (_Float16)w0.w;
        hv[4] = (_Float16)w1.x; hv[5] = (_Float16)w1.y;
        hv[6] = (_Float16)w1.z; hv[7] = (_Float16)w1.w;
        *(half8*)&Wh[row * 128 + ((slot ^ (row & 15)) << 3)] = hv;
    }

    if constexpr (FROM_F16) {
        // phase 1b: straight copy of precomputed f16 log0 rows into swizzled LDS
        #pragma unroll
        for (int i = 0; i < 8; ++i) {
            int c = i * 256 + t;  // 2048 chunks of 8 halves
            int row = c >> 4, slot = c & 15;
            half8 hv = *(const half8*)(y + (size_t)(r0 + row) * 128 + slot * 8);
            *(half8*)&Ah[row * 128 + ((slot ^ (row & 15)) << 3)] = hv;
        }
    } else {
        // phase 1a: log0 rows from f32 x (2 rows per iteration, half-wave each)
        for (int it = 0; it < 16; ++it) {
            int rl = w * 32 + it * 2 + hi;
            const float* xr = x + (size_t)(r0 + rl) * DP;
            float x0 = xr[0];
            float a0 = xr[1 + j];
            float a1 = xr[33 + j];
            float a2 = xr[65 + j];
            float a3 = xr[97 + j];
            float ss = a0 * a0 + a1 * a1 + a2 * a2 + a3 * a3;
            ss += __shfl_xor(ss, 1);
            ss += __shfl_xor(ss, 2);
            ss += __shfl_xor(ss, 4);
            ss += __shfl_xor(ss, 8);
            ss += __shfl_xor(ss, 16);
            float xn = fsqrt(fmaxf(ss, EPSF * EPSF));
            float theta = facosh(fmaxf(x0, 1.0f + EPSF));
            float f = theta * frcp(xn);
            int base = rl * 128;
            int swz = (rl & 15) << 3;
            Ah[base + ((j)      ^ swz)] = (_Float16)(f * a0);
            Ah[base + ((j + 32) ^ swz)] = (_Float16)(f * a1);
            Ah[base + ((j + 64) ^ swz)] = (_Float16)(f * a2);
            Ah[base + ((j + 96) ^ swz)] = (_Float16)(f * a3);
        }
    }
    __syncthreads();

    // main: 8 K-steps x 4 col-tiles of mfma 32x32x16
    int rA = w * 32 + j;                 // (rA & 15) == (j & 15)
    int swzj = (j & 15) << 3;
    const _Float16* Abase = &Ah[rA * 128];
    const _Float16* B0 = &Wh[(j)*128];
    const _Float16* B1 = &Wh[(j + 32) * 128];
    const _Float16* B2 = &Wh[(j + 64) * 128];
    const _Float16* B3 = &Wh[(j + 96) * 128];

    float bv0 = bias[j], bv1 = bias[j + 32], bv2 = bias[j + 64], bv3 = bias[j + 96];
    floatx16 acc0, acc1, acc2, acc3;
    #pragma unroll
    for (int q = 0; q < 16; ++q) {
        acc0[q] = bv0; acc1[q] = bv1; acc2[q] = bv2; acc3[q] = bv3;
    }

    #pragma unroll
    for (int ks = 0; ks < 8; ++ks) {
        int kh = (ks * 16 + hi * 8) ^ swzj;
        half8 a  = *(const half8*)(Abase + kh);
        half8 b0 = *(const half8*)(B0 + kh);
        half8 b1 = *(const half8*)(B1 + kh);
        half8 b2 = *(const half8*)(B2 + kh);
        half8 b3 = *(const half8*)(B3 + kh);
        acc0 = __builtin_amdgcn_mfma_f32_32x32x16_f16(a, b0, acc0, 0, 0, 0);
        acc1 = __builtin_amdgcn_mfma_f32_32x32x16_f16(a, b1, acc1, 0, 0, 0);
        acc2 = __builtin_amdgcn_mfma_f32_32x32x16_f16(a, b2, acc2, 0, 0, 0);
        acc3 = __builtin_amdgcn_mfma_f32_32x32x16_f16(a, b3, acc3, 0, 0, 0);
    }

    // epilogue: pack 4 cols (j, j+32, j+64, j+96) -> one fp8 dword at word j
    #pragma unroll
    for (int q = 0; q < 16; ++q) {
        int row = r0 + w * 32 + (q & 3) + 8 * (q >> 2) + 4 * hi;
        unsigned int u = 0;
        u = (unsigned int)__builtin_amdgcn_cvt_pk_fp8_f32(acc0[q], acc1[q], (int)u, false);
        u = (unsigned int)__builtin_amdgcn_cvt_pk_fp8_f32(acc2[q], acc3[q], (int)u, true);
        zw[(size_t)row * 32 + j] = u;
    }
}

// One wave per node. Wave-uniform values (node, off, deg, edge ids) pinned to
// SGPRs: gather is SGPR row base + lane offset (ushort = 2 fp8 dims/lane).
// Lane l holds cols c0 = (l>>1) + 64*(l&1), c1 = c0 + 32 (z tile-permuted).
// Accumulate as floatx2 -> v_pk_add_f32. WRITE_Y: also emit y2 = log0(result)
// as f16 row-major (feeds layer-2 k_gemm<FROM_F16>).
template <bool WRITE_Y>
__global__ __launch_bounds__(256) void k_agg(const unsigned short* __restrict__ zs,
                                             const float* xin,
                                             const int* __restrict__ off,
                                             const int* __restrict__ deg,
                                             const int* __restrict__ ssrc,
                                             float* out,
                                             _Float16* __restrict__ y2) {
    int wave = threadIdx.x >> 6, lane = threadIdx.x & 63;
    int node = __builtin_amdgcn_readfirstlane(blockIdx.x * 4 + wave);
    int c0 = (lane >> 1) + ((lane & 1) << 6);

    // self loop
    floatx2 acc0 = __builtin_amdgcn_cvt_pk_f32_fp8((int)zs[(size_t)node * 64 + lane], false);
    floatx2 acc1 = {0.f, 0.f}, acc2 = {0.f, 0.f}, acc3 = {0.f, 0.f};

    int start = __builtin_amdgcn_readfirstlane(off[node]);
    int dg = __builtin_amdgcn_readfirstlane(deg[node]);

    for (int c = 0; c < dg; c += 64) {
        int rem = dg - c;
        int m = rem < 64 ? rem : 64;
        int sv = ssrc[start + c + lane];  // ssrc padded by 64 -> no guard
        int j = 0;
        for (; j + 7 < m; j += 8) {
            int s0 = __builtin_amdgcn_readlane(sv, j + 0);
            int s1 = __builtin_amdgcn_readlane(sv, j + 1);
            int s2 = __builtin_amdgcn_readlane(sv, j + 2);
            int s3 = __builtin_amdgcn_readlane(sv, j + 3);
            int s4 = __builtin_amdgcn_readlane(sv, j + 4);
            int s5 = __builtin_amdgcn_readlane(sv, j + 5);
            int s6 = __builtin_amdgcn_readlane(sv, j + 6);
            int s7 = __builtin_amdgcn_readlane(sv, j + 7);
            floatx2 v0 = __builtin_amdgcn_cvt_pk_f32_fp8((int)zs[(size_t)s0 * 64 + lane], false);
            floatx2 v1 = __builtin_amdgcn_cvt_pk_f32_fp8((int)zs[(size_t)s1 * 64 + lane], false);
            floatx2 v2 = __builtin_amdgcn_cvt_pk_f32_fp8((int)zs[(size_t)s2 * 64 + lane], false);
            floatx2 v3 = __builtin_amdgcn_cvt_pk_f32_fp8((int)zs[(size_t)s3 * 64 + lane], false);
            floatx2 v4 = __builtin_amdgcn_cvt_pk_f32_fp8((int)zs[(size_t)s4 * 64 + lane], false);
            floatx2 v5 = __builtin_amdgcn_cvt_pk_f32_fp8((int)zs[(size_t)s5 * 64 + lane], false);
            floatx2 v6 = __builtin_amdgcn_cvt_pk_f32_fp8((int)zs[(size_t)s6 * 64 + lane], false);
            floatx2 v7 = __builtin_amdgcn_cvt_pk_f32_fp8((int)zs[(size_t)s7 * 64 + lane], false);
            acc0 += v0; acc1 += v1; acc2 += v2; acc3 += v3;
            acc0 += v4; acc1 += v5; acc2 += v6; acc3 += v7;
        }
        for (; j < m; ++j) {
            int s = __builtin_amdgcn_readlane(sv, j);
            floatx2 v = __builtin_amdgcn_cvt_pk_f32_fp8((int)zs[(size_t)s * 64 + lane], false);
            acc0 += v;
        }
    }
    floatx2 accT = (acc0 + acc1) + (acc2 + acc3);
    float ax = accT.x, ay = accT.y;

    float inv = frcp((float)(dg + 1));
    float rx = fmaxf(ax * inv, 0.0f);
    float ry = fmaxf(ay * inv, 0.0f);

    // exp0(relu(mean))
    float ss = rx * rx + ry * ry;
    #pragma unroll
    for (int o = 1; o < 64; o <<= 1) ss += __shfl_xor(ss, o);
    float av = fsqrt(fmaxf(ss, EPSF * EPSF));
    float t1 = __expf(av);
    float t1i = frcp(t1);
    float shf = 0.5f * (t1 - t1i) * frcp(av);
    float act0 = 0.5f * (t1 + t1i);
    float asx = shf * rx, asy = shf * ry;

    // load x row (dims c0, c0+32)
    const float* xr = xin + (size_t)node * DP;
    float x0 = xr[0];
    float xsx = xr[1 + c0];
    float xsy = xr[33 + c0];

    // alpha = max(-<x,act>_mink, 1+eps)
    float dot = asx * xsx + asy * xsy;
    #pragma unroll
    for (int o = 1; o < 64; o <<= 1) dot += __shfl_xor(dot, o);
    float mink = dot - act0 * x0;
    float alpha = fmaxf(-mink, 1.0f + EPSF);

    // u = act - alpha*x ; ||u||_mink
    float u0 = act0 - alpha * x0;
    float ux = asx - alpha * xsx;
    float uy = asy - alpha * xsy;
    float uss = ux * ux + uy * uy;
    #pragma unroll
    for (int o = 1; o < 64; o <<= 1) uss += __shfl_xor(uss, o);
    float uu = uss - u0 * u0;
    float un = fsqrt(fmaxf(uu, EPSF * EPSF));

    float d = facosh(alpha);
    float a2 = 0.5f * d;  // beta * dist
    float t2 = __expf(a2);
    float t2i = frcp(t2);
    float ch2 = 0.5f * (t2 + t2i);
    float sh2 = 0.5f * (t2 - t2i) * frcp(un);

    float ox = ch2 * xsx + sh2 * ux;
    float oy = ch2 * xsy + sh2 * uy;

    // proj: recompute time component
    float os = ox * ox + oy * oy;
    #pragma unroll
    for (int o = 1; o < 64; o <<= 1) os += __shfl_xor(os, o);
    float p0 = fsqrt(1.0f + os);

    float* orow = out + (size_t)node * DP;
    if (lane == 0) orow[0] = p0;
    orow[1 + c0] = ox;
    orow[33 + c0] = oy;

    if constexpr (WRITE_Y) {
        // y2 = log0(proj(result)): theta/||o_s|| * o_s  (c=1)
        float theta2 = facosh(fmaxf(p0, 1.0f + EPSF));
        float invn = frcp(fsqrt(fmaxf(os, EPSF * EPSF)));
        float f2 = theta2 * invn;
        _Float16* yr = y2 + (size_t)node * 128;
        yr[c0] = (_Float16)(f2 * ox);
        yr[c0 + 32] = (_Float16)(f2 * oy);
    }
}

extern "C" void kernel_launch(void* const* d_in, const int* in_sizes, int n_in,
                              void* d_out, int out_size, void* d_ws, size_t ws_size,
                              hipStream_t stream) {
    const float* x  = (const float*)d_in[0];
    const int* ei   = (const int*)d_in[1];
    const float* W1 = (const float*)d_in[2];
    const float* b1 = (const float*)d_in[3];
    const float* W2 = (const float*)d_in[4];
    const float* b2 = (const float*)d_in[5];
    float* out = (float*)d_out;

    int n = in_sizes[0] / DP;      // 65536
    int E = in_sizes[1] / 2;       // 1048576
    const int* src = ei;
    const int* dst = ei + E;

    // workspace carve
    char* w = (char*)d_ws;
    unsigned char* z8 = (unsigned char*)w; w += (size_t)n * D;            // fp8 z, 8 MB
    _Float16* y2 = (_Float16*)w;   w += (size_t)n * D * sizeof(_Float16); // f16 log0(h1), 16 MB
    int* deg    = (int*)w;         w += (size_t)n * sizeof(int);
    int* off    = (int*)w;         w += (size_t)n * sizeof(int);
    int* ssrc   = (int*)w;         w += ((size_t)E + 64) * sizeof(int);  // +64 pad
    unsigned int* ebuf = (unsigned int*)w; w += (size_t)E * sizeof(unsigned int);
    int* bcnt   = (int*)w;         w += 256 * sizeof(int);
    int* bbase  = (int*)w;         w += 256 * sizeof(int);
    int* bcur   = (int*)w;         w += 256 * sizeof(int);

    int tb = (E + TILE - 1) / TILE;  // 256

    // CSR build (shared by both layers)
    k_bzero<<<1, 256, 0, stream>>>(bcnt);
    k_bhist<<<tb, 256, 0, stream>>>(dst, E, bcnt);
    k_bscan<<<1, 256, 0, stream>>>(bcnt, bbase, bcur);
    k_bsplit<<<tb, 256, 0, stream>>>(src, dst, E, bcur, ebuf);
    k_csr<<<256, 256, 0, stream>>>(ebuf, bcnt, bbase, deg, off, ssrc);

    // layer 1
    k_gemm<false><<<n / 128, 256, 0, stream>>>(x, nullptr, W1, b1, (unsigned int*)z8);
    k_agg<true><<<n / 4, 256, 0, stream>>>((const unsigned short*)z8, x, off, deg, ssrc, out, y2);

    // layer 2 (A-matrix from fused y2; node-wise part in-place on out)
    k_gemm<true><<<n / 128, 256, 0, stream>>>(nullptr, y2, W2, b2, (unsigned int*)z8);
    k_agg<false><<<n / 4, 256, 0, stream>>>((const unsigned short*)z8, out, off, deg, ssrc, out, nullptr);
}

// Round 12
// 237.042 us; speedup vs baseline: 2.5914x; 1.0287x over previous
//
#include <hip/hip_runtime.h>
#include <hip/hip_bf16.h>
#include <hip/hip_fp16.h>
#include <math.h>

#define NN 65536
#define NE 1048576
#define D 128
#define DP 129
#define EPSF 1e-6f
#define TILE 4096  // edges per block in k_bhist / k_bsplit (16 per thread)

typedef _Float16 half8 __attribute__((ext_vector_type(8)));
typedef float floatx16 __attribute__((ext_vector_type(16)));
typedef float floatx2 __attribute__((ext_vector_type(2)));

__device__ __forceinline__ float frcp(float x) { return __builtin_amdgcn_rcpf(x); }
__device__ __forceinline__ float fsqrt(float x) { return __builtin_amdgcn_sqrtf(x); }
__device__ __forceinline__ float facosh(float x) {
    // x >= 1+eps; log(x + sqrt(x^2-1))
    return __logf(x + fsqrt(fmaxf(x * x - 1.0f, 0.0f)));
}

// ---- CSR build: two-level multisplit (bucket = dst>>8, 256 buckets) ----

__global__ __launch_bounds__(256) void k_bzero(int* __restrict__ bcnt) {
    bcnt[threadIdx.x] = 0;
}

__global__ __launch_bounds__(256) void k_bhist(const int* __restrict__ dst, int E,
                                               int* __restrict__ bcnt) {
    __shared__ int lh[256];
    int t = threadIdx.x;
    lh[t] = 0;
    __syncthreads();
    int base = blockIdx.x * TILE;
    #pragma unroll
    for (int k = 0; k < 16; ++k) {
        int i = base + k * 256 + t;
        if (i < E) atomicAdd(&lh[dst[i] >> 8], 1);
    }
    __syncthreads();
    if (lh[t]) atomicAdd(&bcnt[t], lh[t]);
}

__global__ __launch_bounds__(256) void k_bscan(const int* __restrict__ bcnt,
                                               int* __restrict__ bbase,
                                               int* __restrict__ bcur) {
    __shared__ int sh[256];
    int t = threadIdx.x;
    int v = bcnt[t];
    sh[t] = v;
    __syncthreads();
    for (int o = 1; o < 256; o <<= 1) {
        int u = (t >= o) ? sh[t - o] : 0;
        __syncthreads();
        sh[t] += u;
        __syncthreads();
    }
    int ex = sh[t] - v;
    bbase[t] = ex;
    bcur[t] = ex;
}

// pack (dst&255)<<16 | src  (src < 65536)
__global__ __launch_bounds__(256) void k_bsplit(const int* __restrict__ src,
                                                const int* __restrict__ dst, int E,
                                                int* __restrict__ bcur,
                                                unsigned int* __restrict__ ebuf) {
    __shared__ int lh[256];
    __shared__ int gres[256];
    int t = threadIdx.x;
    lh[t] = 0;
    __syncthreads();
    int base = blockIdx.x * TILE;
    unsigned int pk[16];
    int bk[16], rk[16];
    #pragma unroll
    for (int k = 0; k < 16; ++k) {
        int i = base + k * 256 + t;
        if (i < E) {
            int d = dst[i];
            int b = d >> 8;
            bk[k] = b;
            pk[k] = ((unsigned)(d & 255) << 16) | (unsigned)src[i];
            rk[k] = atomicAdd(&lh[b], 1);
        } else {
            bk[k] = -1; rk[k] = 0; pk[k] = 0;
        }
    }
    __syncthreads();
    gres[t] = lh[t] ? atomicAdd(&bcur[t], lh[t]) : 0;
    __syncthreads();
    #pragma unroll
    for (int k = 0; k < 16; ++k) {
        if (bk[k] >= 0) ebuf[gres[bk[k]] + rk[k]] = pk[k];
    }
}

// one block per bucket: per-node hist/scan -> deg/off, then local scatter of src
__global__ __launch_bounds__(256) void k_csr(const unsigned int* __restrict__ ebuf,
                                             const int* __restrict__ bcnt,
                                             const int* __restrict__ bbase,
                                             int* __restrict__ deg,
                                             int* __restrict__ off,
                                             int* __restrict__ ssrc) {
    __shared__ int lh[256];
    __shared__ int sc[256];
    __shared__ int lcur[256];
    int t = threadIdx.x;
    int b = blockIdx.x;
    int start = bbase[b];
    int cnt = bcnt[b];
    lh[t] = 0;
    __syncthreads();
    for (int i = t; i < cnt; i += 256) {
        unsigned int e = ebuf[start + i];
        atomicAdd(&lh[e >> 16], 1);
    }
    __syncthreads();
    int v = lh[t];
    sc[t] = v;
    __syncthreads();
    for (int o = 1; o < 256; o <<= 1) {
        int u = (t >= o) ? sc[t - o] : 0;
        __syncthreads();
        sc[t] += u;
        __syncthreads();
    }
    int ex = sc[t] - v;
    int node = (b << 8) + t;
    deg[node] = v;
    off[node] = start + ex;
    lcur[t] = ex;
    __syncthreads();
    for (int i = t; i < cnt; i += 256) {
        unsigned int e = ebuf[start + i];
        int d = e >> 16;
        int r = atomicAdd(&lcur[d], 1);
        ssrc[start + r] = (int)(e & 0xFFFFu);
    }
}

// ---- MFMA GEMM: z[r][j] = sum_k A[r][k] * W[j][k] + b[j] ----
// A = log0(x) computed in-kernel (layer 1, FROM_F16=false) or pre-computed
// f16 y rows (layer 2, FROM_F16=true, written by k_agg<WRITE_Y=true>).
// z stored as fp8 e4m3, tile-permuted: dword d of a 128-B row holds cols
// [d, d+32, d+64, d+96] -> C-fragment packs into ONE dword store per row.
// Fragment layouts (mfma_f32_32x32x16_f16):
//   A: row = lane&31, k = (lane>>5)*8 + e ; B: col = lane&31, same k
//   C: col = lane&31, row = (reg&3) + 8*(reg>>2) + 4*(lane>>5)   [m74/m101]
template <bool FROM_F16>
__global__ __launch_bounds__(256) void k_gemm(const float* __restrict__ x,
                                              const _Float16* __restrict__ y,
                                              const float* __restrict__ W,
                                              const float* __restrict__ bias,
                                              unsigned int* __restrict__ zw) {
    __shared__ _Float16 Ah[128 * 128];
    __shared__ _Float16 Wh[128 * 128];
    int t = threadIdx.x;
    int w = t >> 6;
    int l = t & 63;
    int j = l & 31;
    int hi = l >> 5;
    int r0 = blockIdx.x * 128;

    // phase 0: stage W (f32 -> f16), swizzled
    #pragma unroll
    for (int i = 0; i < 8; ++i) {
        int c = i * 256 + t;  // chunk id in [0,2048)
        int row = c >> 4, slot = c & 15;
        const float4* wp = (const float4*)(W + row * 128 + slot * 8);
        float4 w0 = wp[0], w1 = wp[1];
        half8 hv;
        hv[0] = (_Float16)w0.x; hv[1] = (_Float16)w0.y;
        hv[2] = (_Float16)w0.z; hv[3] = (_Float16)w0.w;
        hv[4] = (_Float16)w1.x; hv[5] = (_Float16)w1.y;
        hv[6] = (_Float16)w1.z; hv[7] = (_Float16)w1.w;
        *(half8*)&Wh[row * 128 + ((slot ^ (row & 15)) << 3)] = hv;
    }

    if constexpr (FROM_F16) {
        // phase 1b: straight copy of precomputed f16 log0 rows into swizzled LDS
        #pragma unroll
        for (int i = 0; i < 8; ++i) {
            int c = i * 256 + t;  // 2048 chunks of 8 halves
            int row = c >> 4, slot = c & 15;
            half8 hv = *(const half8*)(y + (size_t)(r0 + row) * 128 + slot * 8);
            *(half8*)&Ah[row * 128 + ((slot ^ (row & 15)) << 3)] = hv;
        }
    } else {
        // phase 1a: log0 rows from f32 x (2 rows per iteration, half-wave each)
        for (int it = 0; it < 16; ++it) {
            int rl = w * 32 + it * 2 + hi;
            const float* xr = x + (size_t)(r0 + rl) * DP;
            float x0 = xr[0];
            float a0 = xr[1 + j];
            float a1 = xr[33 + j];
            float a2 = xr[65 + j];
            float a3 = xr[97 + j];
            float ss = a0 * a0 + a1 * a1 + a2 * a2 + a3 * a3;
            ss += __shfl_xor(ss, 1);
            ss += __shfl_xor(ss, 2);
            ss += __shfl_xor(ss, 4);
            ss += __shfl_xor(ss, 8);
            ss += __shfl_xor(ss, 16);
            float xn = fsqrt(fmaxf(ss, EPSF * EPSF));
            float theta = facosh(fmaxf(x0, 1.0f + EPSF));
            float f = theta * frcp(xn);
            int base = rl * 128;
            int swz = (rl & 15) << 3;
            Ah[base + ((j)      ^ swz)] = (_Float16)(f * a0);
            Ah[base + ((j + 32) ^ swz)] = (_Float16)(f * a1);
            Ah[base + ((j + 64) ^ swz)] = (_Float16)(f * a2);
            Ah[base + ((j + 96) ^ swz)] = (_Float16)(f * a3);
        }
    }
    __syncthreads();

    // main: 8 K-steps x 4 col-tiles of mfma 32x32x16
    int rA = w * 32 + j;                 // (rA & 15) == (j & 15)
    int swzj = (j & 15) << 3;
    const _Float16* Abase = &Ah[rA * 128];
    const _Float16* B0 = &Wh[(j)*128];
    const _Float16* B1 = &Wh[(j + 32) * 128];
    const _Float16* B2 = &Wh[(j + 64) * 128];
    const _Float16* B3 = &Wh[(j + 96) * 128];

    float bv0 = bias[j], bv1 = bias[j + 32], bv2 = bias[j + 64], bv3 = bias[j + 96];
    floatx16 acc0, acc1, acc2, acc3;
    #pragma unroll
    for (int q = 0; q < 16; ++q) {
        acc0[q] = bv0; acc1[q] = bv1; acc2[q] = bv2; acc3[q] = bv3;
    }

    #pragma unroll
    for (int ks = 0; ks < 8; ++ks) {
        int kh = (ks * 16 + hi * 8) ^ swzj;
        half8 a  = *(const half8*)(Abase + kh);
        half8 b0 = *(const half8*)(B0 + kh);
        half8 b1 = *(const half8*)(B1 + kh);
        half8 b2 = *(const half8*)(B2 + kh);
        half8 b3 = *(const half8*)(B3 + kh);
        acc0 = __builtin_amdgcn_mfma_f32_32x32x16_f16(a, b0, acc0, 0, 0, 0);
        acc1 = __builtin_amdgcn_mfma_f32_32x32x16_f16(a, b1, acc1, 0, 0, 0);
        acc2 = __builtin_amdgcn_mfma_f32_32x32x16_f16(a, b2, acc2, 0, 0, 0);
        acc3 = __builtin_amdgcn_mfma_f32_32x32x16_f16(a, b3, acc3, 0, 0, 0);
    }

    // epilogue: pack 4 cols (j, j+32, j+64, j+96) -> one fp8 dword at word j
    #pragma unroll
    for (int q = 0; q < 16; ++q) {
        int row = r0 + w * 32 + (q & 3) + 8 * (q >> 2) + 4 * hi;
        unsigned int u = 0;
        u = (unsigned int)__builtin_amdgcn_cvt_pk_fp8_f32(acc0[q], acc1[q], (int)u, false);
        u = (unsigned int)__builtin_amdgcn_cvt_pk_fp8_f32(acc2[q], acc3[q], (int)u, true);
        zw[(size_t)row * 32 + j] = u;
    }
}

// One wave per node; pair-dword gather: lanes 0-31 load a dword (4 fp8 dims)
// of edge row sA, lanes 32-63 of edge row sB -> one 64-lane load covers TWO
// edges. Lane w (= lane&31) owns dims {w, w+32, w+64, w+96} (z tile-permuted
// dword w). After the loop a shfl_xor(32) merges the two halves; reductions
// are 5-step (within-half). Epilogue stores gated to lanes 0-31.
// WRITE_Y: also emit y2 = log0(result) f16 row-major for layer-2 GEMM.
template <bool WRITE_Y>
__global__ __launch_bounds__(256) void k_agg(const unsigned int* __restrict__ zw,
                                             const float* xin,
                                             const int* __restrict__ off,
                                             const int* __restrict__ deg,
                                             const int* __restrict__ ssrc,
                                             float* out,
                                             _Float16* __restrict__ y2) {
    int wave = threadIdx.x >> 6, lane = threadIdx.x & 63;
    int node = __builtin_amdgcn_readfirstlane(blockIdx.x * 4 + wave);
    int wl = lane & 31;
    bool hiH = lane >= 32;

    // self-loop dword: issue early, consume after the merge
    unsigned int dwS = zw[(size_t)node * 32 + wl];

    floatx2 a0 = {0.f, 0.f}, a1 = {0.f, 0.f};  // dims (wl, wl+32), 2 chains
    floatx2 b0 = {0.f, 0.f}, b1 = {0.f, 0.f};  // dims (wl+64, wl+96)

    int start = __builtin_amdgcn_readfirstlane(off[node]);
    int dg = __builtin_amdgcn_readfirstlane(deg[node]);

    for (int c = 0; c < dg; c += 64) {
        int rem = dg - c;
        int m = rem < 64 ? rem : 64;
        int sv = ssrc[start + c + lane];  // ssrc padded by 64 -> no guard
        int j = 0;
        for (; j + 7 < m; j += 8) {
            int s0 = __builtin_amdgcn_readlane(sv, j + 0);
            int s1 = __builtin_amdgcn_readlane(sv, j + 1);
            int s2 = __builtin_amdgcn_readlane(sv, j + 2);
            int s3 = __builtin_amdgcn_readlane(sv, j + 3);
            int s4 = __builtin_amdgcn_readlane(sv, j + 4);
            int s5 = __builtin_amdgcn_readlane(sv, j + 5);
            int s6 = __builtin_amdgcn_readlane(sv, j + 6);
            int s7 = __builtin_amdgcn_readlane(sv, j + 7);
            int r0 = hiH ? s1 : s0;
            int r1 = hiH ? s3 : s2;
            int r2 = hiH ? s5 : s4;
            int r3 = hiH ? s7 : s6;
            unsigned int d0 = zw[(size_t)r0 * 32 + wl];
            unsigned int d1 = zw[(size_t)r1 * 32 + wl];
            unsigned int d2 = zw[(size_t)r2 * 32 + wl];
            unsigned int d3 = zw[(size_t)r3 * 32 + wl];
            a0 += __builtin_amdgcn_cvt_pk_f32_fp8((int)d0, false);
            b0 += __builtin_amdgcn_cvt_pk_f32_fp8((int)d0, true);
            a1 += __builtin_amdgcn_cvt_pk_f32_fp8((int)d1, false);
            b1 += __builtin_amdgcn_cvt_pk_f32_fp8((int)d1, true);
            a0 += __builtin_amdgcn_cvt_pk_f32_fp8((int)d2, false);
            b0 += __builtin_amdgcn_cvt_pk_f32_fp8((int)d2, true);
            a1 += __builtin_amdgcn_cvt_pk_f32_fp8((int)d3, false);
            b1 += __builtin_amdgcn_cvt_pk_f32_fp8((int)d3, true);
        }
        for (; j + 1 < m; j += 2) {
            int sA = __builtin_amdgcn_readlane(sv, j);
            int sB = __builtin_amdgcn_readlane(sv, j + 1);
            int r = hiH ? sB : sA;
            unsigned int dw = zw[(size_t)r * 32 + wl];
            a0 += __builtin_amdgcn_cvt_pk_f32_fp8((int)dw, false);
            b0 += __builtin_amdgcn_cvt_pk_f32_fp8((int)dw, true);
        }
        if (j < m) {
            int s = __builtin_amdgcn_readlane(sv, j);
            unsigned int dw = zw[(size_t)s * 32 + wl];
            floatx2 va = __builtin_amdgcn_cvt_pk_f32_fp8((int)dw, false);
            floatx2 vb = __builtin_amdgcn_cvt_pk_f32_fp8((int)dw, true);
            if (hiH) { va.x = 0.f; va.y = 0.f; vb.x = 0.f; vb.y = 0.f; }
            a1 += va;
            b1 += vb;
        }
    }
    floatx2 accA = a0 + a1;
    floatx2 accB = b0 + b1;
    // merge the two half-wave partial sums
    accA.x += __shfl_xor(accA.x, 32);
    accA.y += __shfl_xor(accA.y, 32);
    accB.x += __shfl_xor(accB.x, 32);
    accB.y += __shfl_xor(accB.y, 32);
    // self loop
    accA += __builtin_amdgcn_cvt_pk_f32_fp8((int)dwS, false);
    accB += __builtin_amdgcn_cvt_pk_f32_fp8((int)dwS, true);

    float inv = frcp((float)(dg + 1));
    float r0m = fmaxf(accA.x * inv, 0.0f);
    float r1m = fmaxf(accA.y * inv, 0.0f);
    float r2m = fmaxf(accB.x * inv, 0.0f);
    float r3m = fmaxf(accB.y * inv, 0.0f);

    // exp0(relu(mean)) — 5-step reductions (halves hold identical data)
    float ss = r0m * r0m + r1m * r1m + r2m * r2m + r3m * r3m;
    #pragma unroll
    for (int o = 1; o < 32; o <<= 1) ss += __shfl_xor(ss, o);
    float av = fsqrt(fmaxf(ss, EPSF * EPSF));
    float t1 = __expf(av);
    float t1i = frcp(t1);
    float shf = 0.5f * (t1 - t1i) * frcp(av);
    float act0 = 0.5f * (t1 + t1i);
    float as0 = shf * r0m, as1 = shf * r1m, as2 = shf * r2m, as3 = shf * r3m;

    // load x row (dims wl, wl+32, wl+64, wl+96)
    const float* xr = xin + (size_t)node * DP;
    float x0 = xr[0];
    float xs0 = xr[1 + wl];
    float xs1 = xr[33 + wl];
    float xs2 = xr[65 + wl];
    float xs3 = xr[97 + wl];

    // alpha = max(-<x,act>_mink, 1+eps)
    float dot = as0 * xs0 + as1 * xs1 + as2 * xs2 + as3 * xs3;
    #pragma unroll
    for (int o = 1; o < 32; o <<= 1) dot += __shfl_xor(dot, o);
    float mink = dot - act0 * x0;
    float alpha = fmaxf(-mink, 1.0f + EPSF);

    // u = act - alpha*x ; ||u||_mink
    float u0 = act0 - alpha * x0;
    float uv0 = as0 - alpha * xs0;
    float uv1 = as1 - alpha * xs1;
    float uv2 = as2 - alpha * xs2;
    float uv3 = as3 - alpha * xs3;
    float uss = uv0 * uv0 + uv1 * uv1 + uv2 * uv2 + uv3 * uv3;
    #pragma unroll
    for (int o = 1; o < 32; o <<= 1) uss += __shfl_xor(uss, o);
    float uu = uss - u0 * u0;
    float un = fsqrt(fmaxf(uu, EPSF * EPSF));

    float d = facosh(alpha);
    float a2 = 0.5f * d;  // beta * dist
    float t2 = __expf(a2);
    float t2i = frcp(t2);
    float ch2 = 0.5f * (t2 + t2i);
    float sh2 = 0.5f * (t2 - t2i) * frcp(un);

    float o0 = ch2 * xs0 + sh2 * uv0;
    float o1 = ch2 * xs1 + sh2 * uv1;
    float o2 = ch2 * xs2 + sh2 * uv2;
    float o3 = ch2 * xs3 + sh2 * uv3;

    // proj: recompute time component
    float os = o0 * o0 + o1 * o1 + o2 * o2 + o3 * o3;
    #pragma unroll
    for (int o = 1; o < 32; o <<= 1) os += __shfl_xor(os, o);
    float p0 = fsqrt(1.0f + os);

    if (!hiH) {
        float* orow = out + (size_t)node * DP;
        if (wl == 0) orow[0] = p0;
        orow[1 + wl] = o0;
        orow[33 + wl] = o1;
        orow[65 + wl] = o2;
        orow[97 + wl] = o3;

        if constexpr (WRITE_Y) {
            // y2 = log0(proj(result)): theta/||o_s|| * o_s  (c=1)
            float theta2 = facosh(fmaxf(p0, 1.0f + EPSF));
            float invn = frcp(fsqrt(fmaxf(os, EPSF * EPSF)));
            float f2 = theta2 * invn;
            _Float16* yr = y2 + (size_t)node * 128;
            yr[wl] = (_Float16)(f2 * o0);
            yr[wl + 32] = (_Float16)(f2 * o1);
            yr[wl + 64] = (_Float16)(f2 * o2);
            yr[wl + 96] = (_Float16)(f2 * o3);
        }
    }
}

extern "C" void kernel_launch(void* const* d_in, const int* in_sizes, int n_in,
                              void* d_out, int out_size, void* d_ws, size_t ws_size,
                              hipStream_t stream) {
    const float* x  = (const float*)d_in[0];
    const int* ei   = (const int*)d_in[1];
    const float* W1 = (const float*)d_in[2];
    const float* b1 = (const float*)d_in[3];
    const float* W2 = (const float*)d_in[4];
    const float* b2 = (const float*)d_in[5];
    float* out = (float*)d_out;

    int n = in_sizes[0] / DP;      // 65536
    int E = in_sizes[1] / 2;       // 1048576
    const int* src = ei;
    const int* dst = ei + E;

    // workspace carve
    char* w = (char*)d_ws;
    unsigned char* z8 = (unsigned char*)w; w += (size_t)n * D;            // fp8 z, 8 MB
    _Float16* y2 = (_Float16*)w;   w += (size_t)n * D * sizeof(_Float16); // f16 log0(h1), 16 MB
    int* deg    = (int*)w;         w += (size_t)n * sizeof(int);
    int* off    = (int*)w;         w += (size_t)n * sizeof(int);
    int* ssrc   = (int*)w;         w += ((size_t)E + 64) * sizeof(int);  // +64 pad
    unsigned int* ebuf = (unsigned int*)w; w += (size_t)E * sizeof(unsigned int);
    int* bcnt   = (int*)w;         w += 256 * sizeof(int);
    int* bbase  = (int*)w;         w += 256 * sizeof(int);
    int* bcur   = (int*)w;         w += 256 * sizeof(int);

    int tb = (E + TILE - 1) / TILE;  // 256

    // CSR build (shared by both layers)
    k_bzero<<<1, 256, 0, stream>>>(bcnt);
    k_bhist<<<tb, 256, 0, stream>>>(dst, E, bcnt);
    k_bscan<<<1, 256, 0, stream>>>(bcnt, bbase, bcur);
    k_bsplit<<<tb, 256, 0, stream>>>(src, dst, E, bcur, ebuf);
    k_csr<<<256, 256, 0, stream>>>(ebuf, bcnt, bbase, deg, off, ssrc);

    // layer 1
    k_gemm<false><<<n / 128, 256, 0, stream>>>(x, nullptr, W1, b1, (unsigned int*)z8);
    k_agg<true><<<n / 4, 256, 0, stream>>>((const unsigned int*)z8, x, off, deg, ssrc, out, y2);

    // layer 2 (A-matrix from fused y2; node-wise part in-place on out)
    k_gemm<true><<<n / 128, 256, 0, stream>>>(nullptr, y2, W2, b2, (unsigned int*)z8);
    k_agg<false><<<n / 4, 256, 0, stream>>>((const unsigned int*)z8, out, off, deg, ssrc, out, nullptr);
}